// Round 16
// baseline (535.231 us; speedup 1.0000x reference)
//
#include <hip/hip_runtime.h>
#include <math.h>

#define NNODES 50000
#define NEDGES 800000
#define NBLK 196    // ceil(50000/256)
#define GN 3125     // ceil(50000/16)
#define NPASS 4     // node-range passes (12500 nodes -> 50KB LDS hist)
#define PASSN 12500
#define NCH 16      // edge chunks
#define ECHUNK (NEDGES/NCH)   // 50000

typedef __attribute__((ext_vector_type(8))) short s16x8;
typedef __attribute__((ext_vector_type(8))) unsigned short u16x8;
typedef __attribute__((ext_vector_type(4))) float f32x4;

#define TANH_C 2.885390081777927f   // 2*log2(e)

__device__ __forceinline__ float tanh_fast(float x){
  float e = __builtin_amdgcn_exp2f(x*TANH_C);
  return 1.0f - 2.0f*__builtin_amdgcn_rcpf(e+1.0f);
}
__device__ __forceinline__ float sig_fast(float x){
  float e = __builtin_amdgcn_exp2f(-1.4426950408889634f*x);
  return __builtin_amdgcn_rcpf(1.0f+e);
}
__device__ __forceinline__ unsigned short f2b(float f){
  union{float f; unsigned u;} v; v.f = f;
  unsigned r = (v.u + 0x7FFFu + ((v.u>>16)&1u)) >> 16;
  return (unsigned short)r;
}
__device__ __forceinline__ float b2f(unsigned short b){
  union{unsigned u; float f;} v; v.u = ((unsigned)b)<<16; return v.f;
}

// ---------- fused weight prep ----------
__global__ __launch_bounds__(512) void k_prep_all(
    const float* __restrict__ Wi, const float* __restrict__ Wo,
    const float* __restrict__ Wf, const float* __restrict__ Wu,
    const float* __restrict__ Wc, const float* __restrict__ Wl,
    const float* __restrict__ emb_link, const float* __restrict__ bl,
    unsigned short* __restrict__ Wfrag, unsigned short* __restrict__ Wcfrag,
    unsigned short* __restrict__ Wlfrag, unsigned short* __restrict__ lp){
  int b = blockIdx.x, t = threadIdx.x;
  if(b < 512){
    int n = b, k = t;
    const float* W = (n<128)? Wi : (n<256)? Wo : (n<384)? Wf : Wu;
    float v = W[(size_t)k*128 + (n&127)];
    int ks = k>>5, kb = (k>>3)&3, j = k&7;
    int nt = n>>4, lm = n&15;
    int l = lm + 16*kb;
    Wfrag[(size_t)(((ks*32 + nt)*64) + l)*8 + j] = f2b(v);
  } else if(b < 640){
    if(t < 320){
      int n = b-512, k = t;
      float v = (k < 300)? Wc[(size_t)k*128 + n] : 0.f;
      int ks = k>>5, kb = (k>>3)&3, j = k&7;
      int nt = n>>4, lm = n&15;
      int l = lm + 16*kb;
      Wcfrag[(size_t)(((ks*8 + nt)*64) + l)*8 + j] = f2b(v);
    }
  } else if(b < 768){
    if(t < 128){
      int n = b-640, k = t;
      float v = Wl[(size_t)(64+k)*128 + n];
      int ks = k>>5, kb = (k>>3)&3, j = k&7;
      int nt = n>>4, lm = n&15;
      int l = lm + 16*kb;
      Wlfrag[(size_t)(((ks*8 + nt)*64) + l)*8 + j] = f2b(v);
    }
  } else {
    if(t < 128){
      int l = b-768, d = t;
      float acc = bl[d];
      #pragma unroll 8
      for(int k=0;k<64;k++) acc += emb_link[l*64+k]*Wl[k*128+d];
      lp[l*128+d] = f2b(acc*TANH_C);       // pre-scaled for gather tanh
    }
  }
}

// Fused: E1 = tanh(gather(emb_token)@Wc + bc); npart = bf16(TANH_C * (E1 @ Wl[64:192]))
__global__ __launch_bounds__(256,2) void k_ne(const int* __restrict__ i_token,
      const float* __restrict__ emb_token, const unsigned short* __restrict__ Wcfrag,
      const float* __restrict__ bc, const unsigned short* __restrict__ Wlfrag,
      unsigned short* __restrict__ npart){
  __shared__ unsigned short As[64*36];
  __shared__ unsigned short E1[64*132];
  __shared__ int rowidx[64];
  int t = threadIdx.x;
  int m0 = blockIdx.x*64;
  if(t<64){ int m=m0+t; rowidx[t]=(m<NNODES)? i_token[m]:0; }
  int w=t>>6, l=t&63, lm=l&15, kb=l>>4;
  f32x4 acc[2][4];
  #pragma unroll
  for(int c=0;c<2;c++)
    #pragma unroll
    for(int r=0;r<4;r++) acc[c][r]=(f32x4){0.f,0.f,0.f,0.f};
  int sr=t>>2, sp=t&3;
  __syncthreads();
  const float* srcrow = emb_token + (size_t)rowidx[sr]*300;
  for(int ks=0; ks<10; ks++){
    int k0 = ks*32 + sp*8;
    u16x8 v;
    #pragma unroll
    for(int j=0;j<8;j++){ int k=k0+j; v[j] = (k<300)? f2b(srcrow[k]) : (unsigned short)0; }
    if(ks) __syncthreads();
    *(u16x8*)(As + sr*36 + sp*8) = v;
    __syncthreads();
    s16x8 af[4];
    #pragma unroll
    for(int rt=0;rt<4;rt++) af[rt] = *(const s16x8*)(As + (16*rt+lm)*36 + kb*8);
    #pragma unroll
    for(int c=0;c<2;c++){
      int nt = 2*w + c;
      s16x8 bfr = *(const s16x8*)(Wcfrag + (size_t)((ks*8+nt)*64 + l)*8);
      #pragma unroll
      for(int rt=0;rt<4;rt++)
        acc[c][rt] = __builtin_amdgcn_mfma_f32_16x16x32_bf16(af[rt], bfr, acc[c][rt],0,0,0);
    }
  }
  __syncthreads();
  #pragma unroll
  for(int c=0;c<2;c++){
    int d = 16*(2*w+c) + lm;
    float vb = bc[d];
    #pragma unroll
    for(int rt=0;rt<4;rt++)
      #pragma unroll
      for(int reg=0;reg<4;reg++){
        int r = 16*rt + kb*4 + reg;
        E1[r*132 + d] = f2b(tanh_fast(acc[c][rt][reg]+vb));
      }
  }
  __syncthreads();
  f32x4 acc2[2][4];
  #pragma unroll
  for(int c=0;c<2;c++)
    #pragma unroll
    for(int r=0;r<4;r++) acc2[c][r]=(f32x4){0.f,0.f,0.f,0.f};
  #pragma unroll
  for(int ks=0; ks<4; ks++){
    s16x8 af[4];
    #pragma unroll
    for(int rt=0;rt<4;rt++) af[rt] = *(const s16x8*)(E1 + (16*rt+lm)*132 + ks*32 + kb*8);
    #pragma unroll
    for(int c=0;c<2;c++){
      int nt = 2*w + c;
      s16x8 bfr = *(const s16x8*)(Wlfrag + (size_t)((ks*8+nt)*64 + l)*8);
      #pragma unroll
      for(int rt=0;rt<4;rt++)
        acc2[c][rt] = __builtin_amdgcn_mfma_f32_16x16x32_bf16(af[rt], bfr, acc2[c][rt],0,0,0);
    }
  }
  #pragma unroll
  for(int c=0;c<2;c++){
    int d = 16*(2*w+c) + lm;
    #pragma unroll
    for(int rt=0;rt<4;rt++)
      #pragma unroll
      for(int reg=0;reg<4;reg++){
        int m = m0 + 16*rt + kb*4 + reg;
        if(m < NNODES) npart[(size_t)m*128 + d] = f2b(acc2[c][rt][reg]*TANH_C);
      }
  }
}

// ---------------- CSR build: LDS-privatized chunked counting sort ----------------
__global__ __launch_bounds__(1024) void k_count(const int* __restrict__ i_to,
      const int* __restrict__ i_from, int* __restrict__ bhist2,
      int* __restrict__ elrank_to, int* __restrict__ elrank_from){
  __shared__ int hist[PASSN];
  int b = blockIdx.x;
  int dir = b / (NPASS*NCH);
  int rem = b - dir*(NPASS*NCH);
  int p = rem / NCH, ch = rem - p*NCH;
  const int* ids = dir ? i_from : i_to;
  int* elrank = dir ? elrank_from : elrank_to;
  int t = threadIdx.x;
  for(int i=t;i<PASSN;i+=1024) hist[i]=0;
  __syncthreads();
  int base = ch*ECHUNK;
  for(int e=base+t; e<base+ECHUNK; e+=1024){
    int r = ids[e] - p*PASSN;
    if((unsigned)r < PASSN) elrank[e] = atomicAdd(&hist[r],1);
  }
  __syncthreads();
  int* dst = bhist2 + (size_t)b*PASSN;
  for(int i=t;i<PASSN;i+=1024) dst[i]=hist[i];
}

__global__ __launch_bounds__(256) void k_scanA(const int* __restrict__ bhist2,
      int* __restrict__ bsum){
  int b = blockIdx.x; int dir = (b >= NBLK); int bb = dir? b-NBLK : b;
  int t = threadIdx.x;
  int idx = bb*256 + t;
  int c = 0;
  if(idx < NNODES){
    int p = idx/PASSN, ln = idx - p*PASSN;
    const int* src = bhist2 + (size_t)(dir*NPASS*NCH + p*NCH)*PASSN + ln;
    #pragma unroll
    for(int ch=0;ch<NCH;ch++) c += src[ch*PASSN];
  }
  __shared__ int red[256];
  red[t] = c; __syncthreads();
  for(int s=128;s>0;s>>=1){ if(t<s) red[t]+=red[t+s]; __syncthreads(); }
  if(t==0) bsum[b] = red[0];
}

__global__ __launch_bounds__(256) void k_scanBC(const int* __restrict__ bsum,
      const int* __restrict__ bhist2,
      int* __restrict__ off_to, int* __restrict__ end_to,
      int* __restrict__ off_from, int* __restrict__ end_from,
      int* __restrict__ cbase,
      int* __restrict__ bhist, int* __restrict__ lrank_to, int* __restrict__ lrank_from){
  int b = blockIdx.x; int dir = (b >= NBLK); int bb = dir? b-NBLK : b;
  int* off = dir? off_from : off_to;
  int* end = dir? end_from : end_to;
  int* lrank = dir? lrank_from : lrank_to;
  __shared__ int sh[256];
  __shared__ int hist[64];
  int t = threadIdx.x;
  sh[t] = (t < NBLK)? bsum[dir*NBLK + t] : 0;
  if(t < 64) hist[t] = 0;
  __syncthreads();
  for(int d=1; d<256; d<<=1){
    int v = (t>=d)? sh[t-d] : 0;
    __syncthreads(); sh[t] += v; __syncthreads();
  }
  int bpre = (bb==0)? 0 : sh[bb-1];
  __syncthreads();
  int idx = bb*256 + t;
  int vals[NCH];
  int c = 0;
  if(idx < NNODES){
    int p = idx/PASSN, ln = idx - p*PASSN;
    const int* src = bhist2 + (size_t)(dir*NPASS*NCH + p*NCH)*PASSN + ln;
    #pragma unroll
    for(int ch=0;ch<NCH;ch++){ vals[ch] = src[ch*PASSN]; c += vals[ch]; }
  }
  sh[t] = c; __syncthreads();
  for(int d=1; d<256; d<<=1){
    int v = (t>=d)? sh[t-d] : 0;
    __syncthreads(); sh[t] += v; __syncthreads();
  }
  if(idx < NNODES){
    int o = bpre + ((t==0)? 0 : sh[t-1]);
    off[idx] = o;
    end[idx] = o + c;
    int run = o;
    #pragma unroll
    for(int ch=0;ch<NCH;ch++){
      cbase[(size_t)(dir*NCH + ch)*NNODES + idx] = run;
      run += vals[ch];
    }
    lrank[idx] = atomicAdd(&hist[min(c,63)], 1);
  }
  __syncthreads();
  if(t < 64) bhist[dir*64*NBLK + t*NBLK + bb] = hist[t];
}

__global__ __launch_bounds__(256) void k_bscan(const int* __restrict__ bhist, int* __restrict__ boff){
  const int N = 64*NBLK;
  const int CH = (N+255)/256;
  int dir = blockIdx.x;
  __shared__ int part[256];
  int t = threadIdx.x;
  int base = t*CH;
  int s = 0;
  for(int i=0;i<CH;i++){ int id=base+i; if(id<N) s += bhist[dir*N+id]; }
  part[t] = s; __syncthreads();
  for(int d=1; d<256; d<<=1){
    int v = (t>=d)? part[t-d] : 0;
    __syncthreads(); part[t] += v; __syncthreads();
  }
  int run = (t==0)? 0 : part[t-1];
  for(int i=0;i<CH;i++){
    int id = base+i;
    if(id<N){ boff[dir*N+id] = run; run += bhist[dir*N+id]; }
  }
}

__global__ void k_dplace(const int* __restrict__ off_to, const int* __restrict__ end_to,
                         const int* __restrict__ off_from, const int* __restrict__ end_from,
                         const int* __restrict__ boff,
                         const int* __restrict__ lrank_to, const int* __restrict__ lrank_from,
                         int* __restrict__ perm_to, int* __restrict__ perm_from){
  int idx = blockIdx.x*256 + threadIdx.x;
  if(idx >= NNODES) return;
  int blk = idx >> 8;
  int d1 = end_to[idx]-off_to[idx];
  perm_to[ boff[min(d1,63)*NBLK + blk] + lrank_to[idx] ] = idx;
  int d2 = end_from[idx]-off_from[idx];
  perm_from[ boff[64*NBLK + min(d2,63)*NBLK + blk] + lrank_from[idx] ] = idx;
}

__global__ void k_place(const int* __restrict__ i_link, const int* __restrict__ i_from,
                        const int* __restrict__ i_to,
                        const int* __restrict__ cbase,
                        const int* __restrict__ elrank_to, const int* __restrict__ elrank_from,
                        int* __restrict__ pay_to, int* __restrict__ pay_from){
  int e = blockIdx.x*256 + threadIdx.x;
  if(e >= NEDGES) return;
  int il = i_link[e], f = i_from[e], tt = i_to[e];
  int ch = e / ECHUNK;
  pay_to  [ cbase[(size_t)ch*NNODES + tt]            + elrank_to[e] ]   = f  | (il<<16);
  pay_from[ cbase[(size_t)(NCH+ch)*NNODES + f]       + elrank_from[e] ] = tt | (il<<16);
}

// ---------------- gathers (16 lanes/node, degree-sorted, 2x unrolled) ----------------
__global__ __launch_bounds__(256) void k_gather_x(
      const int* __restrict__ off_to, const int* __restrict__ end_to, const int* __restrict__ pay_to,
      const int* __restrict__ off_from, const int* __restrict__ end_from, const int* __restrict__ pay_from,
      const int* __restrict__ perm_to, const int* __restrict__ perm_from,
      const unsigned short* __restrict__ lp, const unsigned short* __restrict__ npart,
      unsigned short* __restrict__ xin, unsigned short* __restrict__ xout){
  int isOut = (blockIdx.x >= GN);
  int bb = isOut? blockIdx.x-GN : blockIdx.x;
  int slot = bb*16 + (threadIdx.x>>4);
  int n = isOut? perm_from[slot] : perm_to[slot];
  int c = (threadIdx.x & 15)*8;
  const int* off = isOut? off_from : off_to;
  const int* end = isOut? end_from : end_to;
  const int* pay = isOut? pay_from : pay_to;
  unsigned short* out = isOut? xout : xin;
  float acc[8];
  #pragma unroll
  for(int q=0;q<8;q++) acc[q]=0.f;
  int s = off[n], e = end[n];
  if(isOut){
    u16x8 bb8 = *(const u16x8*)(npart + (size_t)n*128 + c);
    float bf[8];
    #pragma unroll
    for(int q=0;q<8;q++) bf[q]=b2f(bb8[q]);
    int j = s;
    for(; j+1<e; j+=2){
      int p0 = pay[j], p1 = pay[j+1];
      u16x8 a0 = *(const u16x8*)(lp + (p0>>16)*128 + c);
      u16x8 a1 = *(const u16x8*)(lp + (p1>>16)*128 + c);
      #pragma unroll
      for(int q=0;q<8;q++){
        float e0 = __builtin_amdgcn_exp2f(b2f(a0[q])+bf[q]);
        float e1 = __builtin_amdgcn_exp2f(b2f(a1[q])+bf[q]);
        acc[q] += __builtin_amdgcn_rcpf(e0+1.0f) + __builtin_amdgcn_rcpf(e1+1.0f);
      }
    }
    if(j<e){
      int p0 = pay[j];
      u16x8 a0 = *(const u16x8*)(lp + (p0>>16)*128 + c);
      #pragma unroll
      for(int q=0;q<8;q++){
        float e0 = __builtin_amdgcn_exp2f(b2f(a0[q])+bf[q]);
        acc[q] += __builtin_amdgcn_rcpf(e0+1.0f);
      }
    }
  } else {
    int j = s;
    for(; j+1<e; j+=2){
      int p0 = pay[j], p1 = pay[j+1];
      u16x8 a0 = *(const u16x8*)(lp + (p0>>16)*128 + c);
      u16x8 b0 = *(const u16x8*)(npart + (size_t)(p0&0xFFFF)*128 + c);
      u16x8 a1 = *(const u16x8*)(lp + (p1>>16)*128 + c);
      u16x8 b1 = *(const u16x8*)(npart + (size_t)(p1&0xFFFF)*128 + c);
      #pragma unroll
      for(int q=0;q<8;q++){
        float e0 = __builtin_amdgcn_exp2f(b2f(a0[q])+b2f(b0[q]));
        float e1 = __builtin_amdgcn_exp2f(b2f(a1[q])+b2f(b1[q]));
        acc[q] += __builtin_amdgcn_rcpf(e0+1.0f) + __builtin_amdgcn_rcpf(e1+1.0f);
      }
    }
    if(j<e){
      int p0 = pay[j];
      u16x8 a0 = *(const u16x8*)(lp + (p0>>16)*128 + c);
      u16x8 b0 = *(const u16x8*)(npart + (size_t)(p0&0xFFFF)*128 + c);
      #pragma unroll
      for(int q=0;q<8;q++){
        float e0 = __builtin_amdgcn_exp2f(b2f(a0[q])+b2f(b0[q]));
        acc[q] += __builtin_amdgcn_rcpf(e0+1.0f);
      }
    }
  }
  float deg = (float)(e - s);
  u16x8 o;
  #pragma unroll
  for(int q=0;q<8;q++) o[q]=f2b(deg - 2.0f*acc[q]);
  *(u16x8*)(out + (size_t)n*128 + c) = o;
}

__global__ __launch_bounds__(256) void k_gather_h(
      const int* __restrict__ off_to, const int* __restrict__ end_to, const int* __restrict__ pay_to,
      const int* __restrict__ off_from, const int* __restrict__ end_from, const int* __restrict__ pay_from,
      const int* __restrict__ perm_to, const int* __restrict__ perm_from,
      const unsigned short* __restrict__ src, unsigned short* __restrict__ hin,
      unsigned short* __restrict__ hout){
  int isOut = (blockIdx.x >= GN);
  int bb = isOut? blockIdx.x-GN : blockIdx.x;
  int slot = bb*16 + (threadIdx.x>>4);
  int n = isOut? perm_from[slot] : perm_to[slot];
  int c = (threadIdx.x & 15)*8;
  const int* off = isOut? off_from : off_to;
  const int* end = isOut? end_from : end_to;
  const int* pay = isOut? pay_from : pay_to;
  unsigned short* out = isOut? hout : hin;
  float acc[8];
  #pragma unroll
  for(int q=0;q<8;q++) acc[q]=0.f;
  int s = off[n], e = end[n];
  int j = s;
  for(; j+1<e; j+=2){
    int v0 = pay[j] & 0xFFFF, v1 = pay[j+1] & 0xFFFF;
    u16x8 a0 = *(const u16x8*)(src + (size_t)v0*128 + c);
    u16x8 a1 = *(const u16x8*)(src + (size_t)v1*128 + c);
    #pragma unroll
    for(int q=0;q<8;q++) acc[q] += b2f(a0[q]) + b2f(a1[q]);
  }
  if(j<e){
    int v0 = pay[j] & 0xFFFF;
    u16x8 a0 = *(const u16x8*)(src + (size_t)v0*128 + c);
    #pragma unroll
    for(int q=0;q<8;q++) acc[q] += b2f(a0[q]);
  }
  u16x8 o;
  #pragma unroll
  for(int q=0;q<8;q++) o[q]=f2b(acc[q]);
  *(u16x8*)(out + (size_t)n*128 + c) = o;
}

// ---------------- fused MFMA gate GEMM + LSTM cell (R13 pipeline, 4 waves/EU) ----------------
template<int P>
__device__ __forceinline__ const unsigned short* pick(
    const unsigned short* x0, const unsigned short* x1,
    const unsigned short* x2, const unsigned short* x3, int ks){
  if(P==2) return (ks<4)? x0 : x1;
  return (ks<4)? x0 : (ks<8)? x1 : (ks<12)? x2 : x3;
}

template<int P>
__global__ __launch_bounds__(256,4) void k_gates(
    const unsigned short* __restrict__ x0, const unsigned short* __restrict__ x1,
    const unsigned short* __restrict__ x2, const unsigned short* __restrict__ x3,
    const unsigned short* __restrict__ Wfrag,
    const float* __restrict__ bi, const float* __restrict__ bo,
    const float* __restrict__ bfg, const float* __restrict__ bu,
    unsigned short* __restrict__ c1b, unsigned short* __restrict__ h1,
    float* __restrict__ hout)
{
  __shared__ unsigned short As[2][64*36];
  int t = threadIdx.x;
  int m0 = blockIdx.x*64;
  int w = t>>6; int l = t&63;
  int lm = l&15, kb = l>>4;
  f32x4 acc[2][4][4];
  #pragma unroll
  for(int a=0;a<2;a++)
    #pragma unroll
    for(int g=0;g<4;g++)
      #pragma unroll
      for(int r=0;r<4;r++) acc[a][g][r]=(f32x4){0.f,0.f,0.f,0.f};
  int sr = t>>2, sp = t&3;
  int sm = m0 + sr; if(sm >= NNODES) sm = NNODES-1;
  size_t soff = (size_t)sm*128 + sp*8;
  const int KSTEPS = P*4;
  u16x8 v0 = *(const u16x8*)(pick<P>(x0,x1,x2,x3,0) + soff + 0);
  *(u16x8*)(As[0] + sr*36 + sp*8) = v0;
  u16x8 vn = *(const u16x8*)(pick<P>(x0,x1,x2,x3,1) + soff + 32);
  __syncthreads();
  #pragma unroll
  for(int ks=0; ks<KSTEPS; ks++){
    int cur = ks&1;
    if(ks+1 < KSTEPS) *(u16x8*)(As[cur^1] + sr*36 + sp*8) = vn;
    if(ks+2 < KSTEPS)
      vn = *(const u16x8*)(pick<P>(x0,x1,x2,x3,ks+2) + soff + ((ks+2)&3)*32);
    s16x8 af[4];
    #pragma unroll
    for(int rt=0; rt<4; rt++)
      af[rt] = *(const s16x8*)(As[cur] + (16*rt+lm)*36 + kb*8);
    #pragma unroll
    for(int c=0;c<2;c++){
      #pragma unroll
      for(int g=0;g<4;g++){
        if(P==2 && g==2) continue;     // layer 1: f-gate unused (c_prev = 0)
        int nt = 8*g + 2*w + c;
        s16x8 bfr = *(const s16x8*)(Wfrag + (size_t)((ks*32 + nt)*64 + l)*8);
        #pragma unroll
        for(int rt=0; rt<4; rt++)
          acc[c][g][rt] = __builtin_amdgcn_mfma_f32_16x16x32_bf16(af[rt], bfr, acc[c][g][rt], 0,0,0);
      }
    }
    __syncthreads();
  }
  #pragma unroll
  for(int c=0;c<2;c++){
    int d = 16*(2*w+c) + lm;
    float vbi = bi[d], vbo = bo[d], vbu = bu[d];
    float vbf = (P==4)? bfg[d] : 0.f;
    #pragma unroll
    for(int rt=0; rt<4; rt++){
      #pragma unroll
      for(int reg=0; reg<4; reg++){
        int m = m0 + 16*rt + kb*4 + reg;
        if(m < NNODES){
          size_t o = (size_t)m*128 + d;
          float pi = acc[c][0][rt][reg] + vbi;
          float po = acc[c][1][rt][reg] + vbo;
          float pu = acc[c][3][rt][reg] + vbu;
          if(P==2){
            float c1v = sig_fast(pi)*tanh_fast(pu);
            float hv  = sig_fast(po)*tanh_fast(c1v);
            c1b[o] = f2b(c1v);
            h1[o] = f2b(hv);
          } else {
            float pf = acc[c][2][rt][reg] + vbf;
            float c2 = sig_fast(pf)*b2f(c1b[o]) + sig_fast(pi)*tanh_fast(pu);
            hout[o] = sig_fast(po)*tanh_fast(c2);
          }
        }
      }
    }
  }
}

extern "C" void kernel_launch(void* const* d_in, const int* in_sizes, int n_in,
                              void* d_out, int out_size, void* d_ws, size_t ws_size,
                              hipStream_t stream){
  const int*   i_token  = (const int*)d_in[0];
  const int*   i_link   = (const int*)d_in[1];
  const int*   i_from   = (const int*)d_in[2];
  const int*   i_to     = (const int*)d_in[3];
  const float* emb_token= (const float*)d_in[4];
  const float* emb_link = (const float*)d_in[5];
  const float* Wc = (const float*)d_in[6];  const float* bc = (const float*)d_in[7];
  const float* Wl = (const float*)d_in[8];  const float* bl = (const float*)d_in[9];
  const float* Wi = (const float*)d_in[10]; const float* bi = (const float*)d_in[11];
  const float* Wo = (const float*)d_in[12]; const float* bo = (const float*)d_in[13];
  const float* Wf = (const float*)d_in[14]; const float* bf_ = (const float*)d_in[15];
  const float* Wu = (const float*)d_in[16]; const float* bu = (const float*)d_in[17];
  float* out = (float*)d_out;

  const size_t NB = (size_t)NNODES*128;
  unsigned short* c1b   = (unsigned short*)d_ws;
  unsigned short* npart = c1b + NB;
  unsigned short* xin   = npart + NB;
  unsigned short* xout  = xin + NB;
  unsigned short* hin   = xout + NB;
  unsigned short* houtb = hin + NB;
  unsigned short* h1    = houtb + NB;
  unsigned short* WgT   = h1 + NB;
  unsigned short* Wcfrag = WgT + 512*512;
  unsigned short* Wlfrag = Wcfrag + 320*128;
  unsigned short* linkpart = Wlfrag + 128*128;
  int* ia = (int*)(linkpart + 50*128);
  int* bhist2   = ia;                             // 2*NPASS*NCH*PASSN
  int* cbase    = bhist2 + 2*NPASS*NCH*PASSN;     // 2*NCH*NNODES
  int* off_to   = cbase + 2*NCH*NNODES;
  int* end_to   = off_to + NNODES;
  int* off_from = end_to + NNODES;
  int* end_from = off_from + NNODES;
  int* lrank_to = end_from + NNODES;
  int* lrank_from = lrank_to + NNODES;
  int* perm_to  = lrank_from + NNODES;
  int* perm_from= perm_to + NNODES;
  int* bsum     = perm_from + NNODES;             // 2*NBLK
  int* bhist    = bsum + 2*NBLK;                  // 2*64*NBLK
  int* boff     = bhist + 2*64*NBLK;              // 2*64*NBLK
  int* pay_to   = boff + 2*64*NBLK;
  int* pay_from = pay_to + NEDGES;
  int* elrank_to  = pay_from + NEDGES;
  int* elrank_from= elrank_to + NEDGES;

  const int GB = (NNODES + 63)/64;    // 782
  const int GE = (NEDGES + 255)/256;  // 3125

  // CSR build: LDS-privatized count (no global atomics) + scans + non-atomic place
  k_count<<<2*NPASS*NCH,1024,0,stream>>>(i_to, i_from, bhist2, elrank_to, elrank_from);
  k_scanA<<<2*NBLK,256,0,stream>>>(bhist2, bsum);
  k_scanBC<<<2*NBLK,256,0,stream>>>(bsum, bhist2, off_to, end_to, off_from, end_from,
                                    cbase, bhist, lrank_to, lrank_from);
  k_bscan<<<2,256,0,stream>>>(bhist, boff);
  k_dplace<<<NBLK,256,0,stream>>>(off_to, end_to, off_from, end_from, boff,
                                  lrank_to, lrank_from, perm_to, perm_from);
  k_place<<<GE,256,0,stream>>>(i_link, i_from, i_to, cbase, elrank_to, elrank_from,
                               pay_to, pay_from);

  // weight prepacks + node features
  k_prep_all<<<818,512,0,stream>>>(Wi, Wo, Wf, Wu, Wc, Wl, emb_link, bl,
                                   WgT, Wcfrag, Wlfrag, linkpart);
  k_ne<<<GB,256,0,stream>>>(i_token, emb_token, Wcfrag, bc, Wlfrag, npart);

  // x gathers (degree-sorted)
  k_gather_x<<<2*GN,256,0,stream>>>(off_to, end_to, pay_to, off_from, end_from, pay_from,
                                    perm_to, perm_from, linkpart, npart, xin, xout);

  // layer 1 fused (K=256 over x; f-gate skipped)
  k_gates<2><<<GB,256,0,stream>>>(xin, xout, nullptr, nullptr, WgT,
                                  bi, bo, bf_, bu, c1b, h1, nullptr);

  // h gathers (degree-sorted)
  k_gather_h<<<2*GN,256,0,stream>>>(off_to, end_to, pay_to, off_from, end_from, pay_from,
                                    perm_to, perm_from, h1, hin, houtb);

  // layer 2 fused (K=512)
  k_gates<4><<<GB,256,0,stream>>>(xin, xout, hin, houtb, WgT,
                                  bi, bo, bf_, bu, c1b, nullptr, out);
}

// Round 17
// 316.076 us; speedup vs baseline: 1.6934x; 1.6934x over previous
//
#include <hip/hip_runtime.h>
#include <math.h>

#define NNODES 50000
#define NEDGES 800000
#define NBLK 196    // ceil(50000/256)
#define GN 3125     // ceil(50000/16)
#define NPASS 4     // node-range passes (12500 nodes -> 50KB LDS hist)
#define PASSN 12500
#define NCH 16      // edge chunks
#define ECHUNK (NEDGES/NCH)   // 50000

typedef __attribute__((ext_vector_type(8))) short s16x8;
typedef __attribute__((ext_vector_type(8))) unsigned short u16x8;
typedef __attribute__((ext_vector_type(4))) float f32x4;

#define TANH_C 2.885390081777927f   // 2*log2(e)

__device__ __forceinline__ float tanh_fast(float x){
  float e = __builtin_amdgcn_exp2f(x*TANH_C);
  return 1.0f - 2.0f*__builtin_amdgcn_rcpf(e+1.0f);
}
__device__ __forceinline__ float sig_fast(float x){
  float e = __builtin_amdgcn_exp2f(-1.4426950408889634f*x);
  return __builtin_amdgcn_rcpf(1.0f+e);
}
__device__ __forceinline__ unsigned short f2b(float f){
  union{float f; unsigned u;} v; v.f = f;
  unsigned r = (v.u + 0x7FFFu + ((v.u>>16)&1u)) >> 16;
  return (unsigned short)r;
}
__device__ __forceinline__ float b2f(unsigned short b){
  union{unsigned u; float f;} v; v.u = ((unsigned)b)<<16; return v.f;
}

// ---------- fused weight prep ----------
__global__ __launch_bounds__(512) void k_prep_all(
    const float* __restrict__ Wi, const float* __restrict__ Wo,
    const float* __restrict__ Wf, const float* __restrict__ Wu,
    const float* __restrict__ Wc, const float* __restrict__ Wl,
    const float* __restrict__ emb_link, const float* __restrict__ bl,
    unsigned short* __restrict__ Wfrag, unsigned short* __restrict__ Wcfrag,
    unsigned short* __restrict__ Wlfrag, unsigned short* __restrict__ lp){
  int b = blockIdx.x, t = threadIdx.x;
  if(b < 512){
    int n = b, k = t;
    const float* W = (n<128)? Wi : (n<256)? Wo : (n<384)? Wf : Wu;
    float v = W[(size_t)k*128 + (n&127)];
    int ks = k>>5, kb = (k>>3)&3, j = k&7;
    int nt = n>>4, lm = n&15;
    int l = lm + 16*kb;
    Wfrag[(size_t)(((ks*32 + nt)*64) + l)*8 + j] = f2b(v);
  } else if(b < 640){
    if(t < 320){
      int n = b-512, k = t;
      float v = (k < 300)? Wc[(size_t)k*128 + n] : 0.f;
      int ks = k>>5, kb = (k>>3)&3, j = k&7;
      int nt = n>>4, lm = n&15;
      int l = lm + 16*kb;
      Wcfrag[(size_t)(((ks*8 + nt)*64) + l)*8 + j] = f2b(v);
    }
  } else if(b < 768){
    if(t < 128){
      int n = b-640, k = t;
      float v = Wl[(size_t)(64+k)*128 + n];
      int ks = k>>5, kb = (k>>3)&3, j = k&7;
      int nt = n>>4, lm = n&15;
      int l = lm + 16*kb;
      Wlfrag[(size_t)(((ks*8 + nt)*64) + l)*8 + j] = f2b(v);
    }
  } else {
    if(t < 128){
      int l = b-768, d = t;
      float acc = bl[d];
      #pragma unroll 8
      for(int k=0;k<64;k++) acc += emb_link[l*64+k]*Wl[k*128+d];
      lp[l*128+d] = f2b(acc*TANH_C);       // pre-scaled for gather tanh
    }
  }
}

// Fused: E1 = tanh(gather(emb_token)@Wc + bc); npart = bf16(TANH_C * (E1 @ Wl[64:192]))
__global__ __launch_bounds__(256,2) void k_ne(const int* __restrict__ i_token,
      const float* __restrict__ emb_token, const unsigned short* __restrict__ Wcfrag,
      const float* __restrict__ bc, const unsigned short* __restrict__ Wlfrag,
      unsigned short* __restrict__ npart){
  __shared__ unsigned short As[64*36];
  __shared__ unsigned short E1[64*132];
  __shared__ int rowidx[64];
  int t = threadIdx.x;
  int m0 = blockIdx.x*64;
  if(t<64){ int m=m0+t; rowidx[t]=(m<NNODES)? i_token[m]:0; }
  int w=t>>6, l=t&63, lm=l&15, kb=l>>4;
  f32x4 acc[2][4];
  #pragma unroll
  for(int c=0;c<2;c++)
    #pragma unroll
    for(int r=0;r<4;r++) acc[c][r]=(f32x4){0.f,0.f,0.f,0.f};
  int sr=t>>2, sp=t&3;
  __syncthreads();
  const float* srcrow = emb_token + (size_t)rowidx[sr]*300;
  for(int ks=0; ks<10; ks++){
    int k0 = ks*32 + sp*8;
    u16x8 v;
    #pragma unroll
    for(int j=0;j<8;j++){ int k=k0+j; v[j] = (k<300)? f2b(srcrow[k]) : (unsigned short)0; }
    if(ks) __syncthreads();
    *(u16x8*)(As + sr*36 + sp*8) = v;
    __syncthreads();
    s16x8 af[4];
    #pragma unroll
    for(int rt=0;rt<4;rt++) af[rt] = *(const s16x8*)(As + (16*rt+lm)*36 + kb*8);
    #pragma unroll
    for(int c=0;c<2;c++){
      int nt = 2*w + c;
      s16x8 bfr = *(const s16x8*)(Wcfrag + (size_t)((ks*8+nt)*64 + l)*8);
      #pragma unroll
      for(int rt=0;rt<4;rt++)
        acc[c][rt] = __builtin_amdgcn_mfma_f32_16x16x32_bf16(af[rt], bfr, acc[c][rt],0,0,0);
    }
  }
  __syncthreads();
  #pragma unroll
  for(int c=0;c<2;c++){
    int d = 16*(2*w+c) + lm;
    float vb = bc[d];
    #pragma unroll
    for(int rt=0;rt<4;rt++)
      #pragma unroll
      for(int reg=0;reg<4;reg++){
        int r = 16*rt + kb*4 + reg;
        E1[r*132 + d] = f2b(tanh_fast(acc[c][rt][reg]+vb));
      }
  }
  __syncthreads();
  f32x4 acc2[2][4];
  #pragma unroll
  for(int c=0;c<2;c++)
    #pragma unroll
    for(int r=0;r<4;r++) acc2[c][r]=(f32x4){0.f,0.f,0.f,0.f};
  #pragma unroll
  for(int ks=0; ks<4; ks++){
    s16x8 af[4];
    #pragma unroll
    for(int rt=0;rt<4;rt++) af[rt] = *(const s16x8*)(E1 + (16*rt+lm)*132 + ks*32 + kb*8);
    #pragma unroll
    for(int c=0;c<2;c++){
      int nt = 2*w + c;
      s16x8 bfr = *(const s16x8*)(Wlfrag + (size_t)((ks*8+nt)*64 + l)*8);
      #pragma unroll
      for(int rt=0;rt<4;rt++)
        acc2[c][rt] = __builtin_amdgcn_mfma_f32_16x16x32_bf16(af[rt], bfr, acc2[c][rt],0,0,0);
    }
  }
  #pragma unroll
  for(int c=0;c<2;c++){
    int d = 16*(2*w+c) + lm;
    #pragma unroll
    for(int rt=0;rt<4;rt++)
      #pragma unroll
      for(int reg=0;reg<4;reg++){
        int m = m0 + 16*rt + kb*4 + reg;
        if(m < NNODES) npart[(size_t)m*128 + d] = f2b(acc2[c][rt][reg]*TANH_C);
      }
  }
}

// ---------------- CSR build: LDS-privatized chunked counting sort ----------------
__global__ __launch_bounds__(1024) void k_count(const int* __restrict__ i_to,
      const int* __restrict__ i_from, int* __restrict__ bhist2,
      int* __restrict__ elrank_to, int* __restrict__ elrank_from){
  __shared__ int hist[PASSN];
  int b = blockIdx.x;
  int dir = b / (NPASS*NCH);
  int rem = b - dir*(NPASS*NCH);
  int p = rem / NCH, ch = rem - p*NCH;
  const int* ids = dir ? i_from : i_to;
  int* elrank = dir ? elrank_from : elrank_to;
  int t = threadIdx.x;
  for(int i=t;i<PASSN;i+=1024) hist[i]=0;
  __syncthreads();
  int base = ch*ECHUNK;
  for(int e=base+t; e<base+ECHUNK; e+=1024){
    int r = ids[e] - p*PASSN;
    if((unsigned)r < PASSN) elrank[e] = atomicAdd(&hist[r],1);
  }
  __syncthreads();
  int* dst = bhist2 + (size_t)b*PASSN;
  for(int i=t;i<PASSN;i+=1024) dst[i]=hist[i];
}

__global__ __launch_bounds__(256) void k_scanA(const int* __restrict__ bhist2,
      int* __restrict__ bsum){
  int b = blockIdx.x; int dir = (b >= NBLK); int bb = dir? b-NBLK : b;
  int t = threadIdx.x;
  int idx = bb*256 + t;
  int c = 0;
  if(idx < NNODES){
    int p = idx/PASSN, ln = idx - p*PASSN;
    const int* src = bhist2 + (size_t)(dir*NPASS*NCH + p*NCH)*PASSN + ln;
    #pragma unroll
    for(int ch=0;ch<NCH;ch++) c += src[ch*PASSN];
  }
  __shared__ int red[256];
  red[t] = c; __syncthreads();
  for(int s=128;s>0;s>>=1){ if(t<s) red[t]+=red[t+s]; __syncthreads(); }
  if(t==0) bsum[b] = red[0];
}

__global__ __launch_bounds__(256) void k_scanBC(const int* __restrict__ bsum,
      const int* __restrict__ bhist2,
      int* __restrict__ off_to, int* __restrict__ end_to,
      int* __restrict__ off_from, int* __restrict__ end_from,
      int* __restrict__ cbase,
      int* __restrict__ bhist, int* __restrict__ lrank_to, int* __restrict__ lrank_from){
  int b = blockIdx.x; int dir = (b >= NBLK); int bb = dir? b-NBLK : b;
  int* off = dir? off_from : off_to;
  int* end = dir? end_from : end_to;
  int* lrank = dir? lrank_from : lrank_to;
  __shared__ int sh[256];
  __shared__ int hist[64];
  int t = threadIdx.x;
  sh[t] = (t < NBLK)? bsum[dir*NBLK + t] : 0;
  if(t < 64) hist[t] = 0;
  __syncthreads();
  for(int d=1; d<256; d<<=1){
    int v = (t>=d)? sh[t-d] : 0;
    __syncthreads(); sh[t] += v; __syncthreads();
  }
  int bpre = (bb==0)? 0 : sh[bb-1];
  __syncthreads();
  int idx = bb*256 + t;
  int vals[NCH];
  int c = 0;
  if(idx < NNODES){
    int p = idx/PASSN, ln = idx - p*PASSN;
    const int* src = bhist2 + (size_t)(dir*NPASS*NCH + p*NCH)*PASSN + ln;
    #pragma unroll
    for(int ch=0;ch<NCH;ch++){ vals[ch] = src[ch*PASSN]; c += vals[ch]; }
  }
  sh[t] = c; __syncthreads();
  for(int d=1; d<256; d<<=1){
    int v = (t>=d)? sh[t-d] : 0;
    __syncthreads(); sh[t] += v; __syncthreads();
  }
  if(idx < NNODES){
    int o = bpre + ((t==0)? 0 : sh[t-1]);
    off[idx] = o;
    end[idx] = o + c;
    int run = o;
    #pragma unroll
    for(int ch=0;ch<NCH;ch++){
      cbase[(size_t)(dir*NCH + ch)*NNODES + idx] = run;
      run += vals[ch];
    }
    lrank[idx] = atomicAdd(&hist[min(c,63)], 1);
  }
  __syncthreads();
  if(t < 64) bhist[dir*64*NBLK + t*NBLK + bb] = hist[t];
}

__global__ __launch_bounds__(256) void k_bscan(const int* __restrict__ bhist, int* __restrict__ boff){
  const int N = 64*NBLK;
  const int CH = (N+255)/256;
  int dir = blockIdx.x;
  __shared__ int part[256];
  int t = threadIdx.x;
  int base = t*CH;
  int s = 0;
  for(int i=0;i<CH;i++){ int id=base+i; if(id<N) s += bhist[dir*N+id]; }
  part[t] = s; __syncthreads();
  for(int d=1; d<256; d<<=1){
    int v = (t>=d)? part[t-d] : 0;
    __syncthreads(); part[t] += v; __syncthreads();
  }
  int run = (t==0)? 0 : part[t-1];
  for(int i=0;i<CH;i++){
    int id = base+i;
    if(id<N){ boff[dir*N+id] = run; run += bhist[dir*N+id]; }
  }
}

__global__ void k_dplace(const int* __restrict__ off_to, const int* __restrict__ end_to,
                         const int* __restrict__ off_from, const int* __restrict__ end_from,
                         const int* __restrict__ boff,
                         const int* __restrict__ lrank_to, const int* __restrict__ lrank_from,
                         int* __restrict__ perm_to, int* __restrict__ perm_from){
  int idx = blockIdx.x*256 + threadIdx.x;
  if(idx >= NNODES) return;
  int blk = idx >> 8;
  int d1 = end_to[idx]-off_to[idx];
  perm_to[ boff[min(d1,63)*NBLK + blk] + lrank_to[idx] ] = idx;
  int d2 = end_from[idx]-off_from[idx];
  perm_from[ boff[64*NBLK + min(d2,63)*NBLK + blk] + lrank_from[idx] ] = idx;
}

__global__ void k_place(const int* __restrict__ i_link, const int* __restrict__ i_from,
                        const int* __restrict__ i_to,
                        const int* __restrict__ cbase,
                        const int* __restrict__ elrank_to, const int* __restrict__ elrank_from,
                        int* __restrict__ pay_to, int* __restrict__ pay_from){
  int e = blockIdx.x*256 + threadIdx.x;
  if(e >= NEDGES) return;
  int il = i_link[e], f = i_from[e], tt = i_to[e];
  int ch = e / ECHUNK;
  pay_to  [ cbase[(size_t)ch*NNODES + tt]            + elrank_to[e] ]   = f  | (il<<16);
  pay_from[ cbase[(size_t)(NCH+ch)*NNODES + f]       + elrank_from[e] ] = tt | (il<<16);
}

// ---------------- gathers (16 lanes/node, degree-sorted, 2x unrolled) ----------------
__global__ __launch_bounds__(256) void k_gather_x(
      const int* __restrict__ off_to, const int* __restrict__ end_to, const int* __restrict__ pay_to,
      const int* __restrict__ off_from, const int* __restrict__ end_from, const int* __restrict__ pay_from,
      const int* __restrict__ perm_to, const int* __restrict__ perm_from,
      const unsigned short* __restrict__ lp, const unsigned short* __restrict__ npart,
      unsigned short* __restrict__ xin, unsigned short* __restrict__ xout){
  int isOut = (blockIdx.x >= GN);
  int bb = isOut? blockIdx.x-GN : blockIdx.x;
  int slot = bb*16 + (threadIdx.x>>4);
  int n = isOut? perm_from[slot] : perm_to[slot];
  int c = (threadIdx.x & 15)*8;
  const int* off = isOut? off_from : off_to;
  const int* end = isOut? end_from : end_to;
  const int* pay = isOut? pay_from : pay_to;
  unsigned short* out = isOut? xout : xin;
  float acc[8];
  #pragma unroll
  for(int q=0;q<8;q++) acc[q]=0.f;
  int s = off[n], e = end[n];
  if(isOut){
    u16x8 bb8 = *(const u16x8*)(npart + (size_t)n*128 + c);
    float bf[8];
    #pragma unroll
    for(int q=0;q<8;q++) bf[q]=b2f(bb8[q]);
    int j = s;
    for(; j+1<e; j+=2){
      int p0 = pay[j], p1 = pay[j+1];
      u16x8 a0 = *(const u16x8*)(lp + (p0>>16)*128 + c);
      u16x8 a1 = *(const u16x8*)(lp + (p1>>16)*128 + c);
      #pragma unroll
      for(int q=0;q<8;q++){
        float e0 = __builtin_amdgcn_exp2f(b2f(a0[q])+bf[q]);
        float e1 = __builtin_amdgcn_exp2f(b2f(a1[q])+bf[q]);
        acc[q] += __builtin_amdgcn_rcpf(e0+1.0f) + __builtin_amdgcn_rcpf(e1+1.0f);
      }
    }
    if(j<e){
      int p0 = pay[j];
      u16x8 a0 = *(const u16x8*)(lp + (p0>>16)*128 + c);
      #pragma unroll
      for(int q=0;q<8;q++){
        float e0 = __builtin_amdgcn_exp2f(b2f(a0[q])+bf[q]);
        acc[q] += __builtin_amdgcn_rcpf(e0+1.0f);
      }
    }
  } else {
    int j = s;
    for(; j+1<e; j+=2){
      int p0 = pay[j], p1 = pay[j+1];
      u16x8 a0 = *(const u16x8*)(lp + (p0>>16)*128 + c);
      u16x8 b0 = *(const u16x8*)(npart + (size_t)(p0&0xFFFF)*128 + c);
      u16x8 a1 = *(const u16x8*)(lp + (p1>>16)*128 + c);
      u16x8 b1 = *(const u16x8*)(npart + (size_t)(p1&0xFFFF)*128 + c);
      #pragma unroll
      for(int q=0;q<8;q++){
        float e0 = __builtin_amdgcn_exp2f(b2f(a0[q])+b2f(b0[q]));
        float e1 = __builtin_amdgcn_exp2f(b2f(a1[q])+b2f(b1[q]));
        acc[q] += __builtin_amdgcn_rcpf(e0+1.0f) + __builtin_amdgcn_rcpf(e1+1.0f);
      }
    }
    if(j<e){
      int p0 = pay[j];
      u16x8 a0 = *(const u16x8*)(lp + (p0>>16)*128 + c);
      u16x8 b0 = *(const u16x8*)(npart + (size_t)(p0&0xFFFF)*128 + c);
      #pragma unroll
      for(int q=0;q<8;q++){
        float e0 = __builtin_amdgcn_exp2f(b2f(a0[q])+b2f(b0[q]));
        acc[q] += __builtin_amdgcn_rcpf(e0+1.0f);
      }
    }
  }
  float deg = (float)(e - s);
  u16x8 o;
  #pragma unroll
  for(int q=0;q<8;q++) o[q]=f2b(deg - 2.0f*acc[q]);
  *(u16x8*)(out + (size_t)n*128 + c) = o;
}

__global__ __launch_bounds__(256) void k_gather_h(
      const int* __restrict__ off_to, const int* __restrict__ end_to, const int* __restrict__ pay_to,
      const int* __restrict__ off_from, const int* __restrict__ end_from, const int* __restrict__ pay_from,
      const int* __restrict__ perm_to, const int* __restrict__ perm_from,
      const unsigned short* __restrict__ src, unsigned short* __restrict__ hin,
      unsigned short* __restrict__ hout){
  int isOut = (blockIdx.x >= GN);
  int bb = isOut? blockIdx.x-GN : blockIdx.x;
  int slot = bb*16 + (threadIdx.x>>4);
  int n = isOut? perm_from[slot] : perm_to[slot];
  int c = (threadIdx.x & 15)*8;
  const int* off = isOut? off_from : off_to;
  const int* end = isOut? end_from : end_to;
  const int* pay = isOut? pay_from : pay_to;
  unsigned short* out = isOut? hout : hin;
  float acc[8];
  #pragma unroll
  for(int q=0;q<8;q++) acc[q]=0.f;
  int s = off[n], e = end[n];
  int j = s;
  for(; j+1<e; j+=2){
    int v0 = pay[j] & 0xFFFF, v1 = pay[j+1] & 0xFFFF;
    u16x8 a0 = *(const u16x8*)(src + (size_t)v0*128 + c);
    u16x8 a1 = *(const u16x8*)(src + (size_t)v1*128 + c);
    #pragma unroll
    for(int q=0;q<8;q++) acc[q] += b2f(a0[q]) + b2f(a1[q]);
  }
  if(j<e){
    int v0 = pay[j] & 0xFFFF;
    u16x8 a0 = *(const u16x8*)(src + (size_t)v0*128 + c);
    #pragma unroll
    for(int q=0;q<8;q++) acc[q] += b2f(a0[q]);
  }
  u16x8 o;
  #pragma unroll
  for(int q=0;q<8;q++) o[q]=f2b(acc[q]);
  *(u16x8*)(out + (size_t)n*128 + c) = o;
}

// ---------------- fused MFMA gate GEMM + LSTM cell (R13 pipeline, 2 waves/EU) ----------------
template<int P>
__device__ __forceinline__ const unsigned short* pick(
    const unsigned short* x0, const unsigned short* x1,
    const unsigned short* x2, const unsigned short* x3, int ks){
  if(P==2) return (ks<4)? x0 : x1;
  return (ks<4)? x0 : (ks<8)? x1 : (ks<12)? x2 : x3;
}

template<int P>
__global__ __launch_bounds__(256,2) void k_gates(
    const unsigned short* __restrict__ x0, const unsigned short* __restrict__ x1,
    const unsigned short* __restrict__ x2, const unsigned short* __restrict__ x3,
    const unsigned short* __restrict__ Wfrag,
    const float* __restrict__ bi, const float* __restrict__ bo,
    const float* __restrict__ bfg, const float* __restrict__ bu,
    unsigned short* __restrict__ c1b, unsigned short* __restrict__ h1,
    float* __restrict__ hout)
{
  __shared__ unsigned short As[2][64*36];
  int t = threadIdx.x;
  int m0 = blockIdx.x*64;
  int w = t>>6; int l = t&63;
  int lm = l&15, kb = l>>4;
  f32x4 acc[2][4][4];
  #pragma unroll
  for(int a=0;a<2;a++)
    #pragma unroll
    for(int g=0;g<4;g++)
      #pragma unroll
      for(int r=0;r<4;r++) acc[a][g][r]=(f32x4){0.f,0.f,0.f,0.f};
  int sr = t>>2, sp = t&3;
  int sm = m0 + sr; if(sm >= NNODES) sm = NNODES-1;
  size_t soff = (size_t)sm*128 + sp*8;
  const int KSTEPS = P*4;
  u16x8 v0 = *(const u16x8*)(pick<P>(x0,x1,x2,x3,0) + soff + 0);
  *(u16x8*)(As[0] + sr*36 + sp*8) = v0;
  u16x8 vn = *(const u16x8*)(pick<P>(x0,x1,x2,x3,1) + soff + 32);
  __syncthreads();
  #pragma unroll
  for(int ks=0; ks<KSTEPS; ks++){
    int cur = ks&1;
    if(ks+1 < KSTEPS) *(u16x8*)(As[cur^1] + sr*36 + sp*8) = vn;
    if(ks+2 < KSTEPS)
      vn = *(const u16x8*)(pick<P>(x0,x1,x2,x3,ks+2) + soff + ((ks+2)&3)*32);
    s16x8 af[4];
    #pragma unroll
    for(int rt=0; rt<4; rt++)
      af[rt] = *(const s16x8*)(As[cur] + (16*rt+lm)*36 + kb*8);
    #pragma unroll
    for(int c=0;c<2;c++){
      #pragma unroll
      for(int g=0;g<4;g++){
        if(P==2 && g==2) continue;     // layer 1: f-gate unused (c_prev = 0)
        int nt = 8*g + 2*w + c;
        s16x8 bfr = *(const s16x8*)(Wfrag + (size_t)((ks*32 + nt)*64 + l)*8);
        #pragma unroll
        for(int rt=0; rt<4; rt++)
          acc[c][g][rt] = __builtin_amdgcn_mfma_f32_16x16x32_bf16(af[rt], bfr, acc[c][g][rt], 0,0,0);
      }
    }
    __syncthreads();
  }
  #pragma unroll
  for(int c=0;c<2;c++){
    int d = 16*(2*w+c) + lm;
    float vbi = bi[d], vbo = bo[d], vbu = bu[d];
    float vbf = (P==4)? bfg[d] : 0.f;
    #pragma unroll
    for(int rt=0; rt<4; rt++){
      #pragma unroll
      for(int reg=0; reg<4; reg++){
        int m = m0 + 16*rt + kb*4 + reg;
        if(m < NNODES){
          size_t o = (size_t)m*128 + d;
          float pi = acc[c][0][rt][reg] + vbi;
          float po = acc[c][1][rt][reg] + vbo;
          float pu = acc[c][3][rt][reg] + vbu;
          if(P==2){
            float c1v = sig_fast(pi)*tanh_fast(pu);
            float hv  = sig_fast(po)*tanh_fast(c1v);
            c1b[o] = f2b(c1v);
            h1[o] = f2b(hv);
          } else {
            float pf = acc[c][2][rt][reg] + vbf;
            float c2 = sig_fast(pf)*b2f(c1b[o]) + sig_fast(pi)*tanh_fast(pu);
            hout[o] = sig_fast(po)*tanh_fast(c2);
          }
        }
      }
    }
  }
}

extern "C" void kernel_launch(void* const* d_in, const int* in_sizes, int n_in,
                              void* d_out, int out_size, void* d_ws, size_t ws_size,
                              hipStream_t stream){
  const int*   i_token  = (const int*)d_in[0];
  const int*   i_link   = (const int*)d_in[1];
  const int*   i_from   = (const int*)d_in[2];
  const int*   i_to     = (const int*)d_in[3];
  const float* emb_token= (const float*)d_in[4];
  const float* emb_link = (const float*)d_in[5];
  const float* Wc = (const float*)d_in[6];  const float* bc = (const float*)d_in[7];
  const float* Wl = (const float*)d_in[8];  const float* bl = (const float*)d_in[9];
  const float* Wi = (const float*)d_in[10]; const float* bi = (const float*)d_in[11];
  const float* Wo = (const float*)d_in[12]; const float* bo = (const float*)d_in[13];
  const float* Wf = (const float*)d_in[14]; const float* bf_ = (const float*)d_in[15];
  const float* Wu = (const float*)d_in[16]; const float* bu = (const float*)d_in[17];
  float* out = (float*)d_out;

  const size_t NB = (size_t)NNODES*128;
  unsigned short* c1b   = (unsigned short*)d_ws;
  unsigned short* npart = c1b + NB;
  unsigned short* xin   = npart + NB;
  unsigned short* xout  = xin + NB;
  unsigned short* hin   = xout + NB;
  unsigned short* houtb = hin + NB;
  unsigned short* h1    = houtb + NB;
  unsigned short* WgT   = h1 + NB;
  unsigned short* Wcfrag = WgT + 512*512;
  unsigned short* Wlfrag = Wcfrag + 320*128;
  unsigned short* linkpart = Wlfrag + 128*128;
  int* ia = (int*)(linkpart + 50*128);
  int* bhist2   = ia;                             // 2*NPASS*NCH*PASSN
  int* cbase    = bhist2 + 2*NPASS*NCH*PASSN;     // 2*NCH*NNODES
  int* off_to   = cbase + 2*NCH*NNODES;
  int* end_to   = off_to + NNODES;
  int* off_from = end_to + NNODES;
  int* end_from = off_from + NNODES;
  int* lrank_to = end_from + NNODES;
  int* lrank_from = lrank_to + NNODES;
  int* perm_to  = lrank_from + NNODES;
  int* perm_from= perm_to + NNODES;
  int* bsum     = perm_from + NNODES;             // 2*NBLK
  int* bhist    = bsum + 2*NBLK;                  // 2*64*NBLK
  int* boff     = bhist + 2*64*NBLK;              // 2*64*NBLK
  int* pay_to   = boff + 2*64*NBLK;
  int* pay_from = pay_to + NEDGES;
  int* elrank_to  = pay_from + NEDGES;
  int* elrank_from= elrank_to + NEDGES;

  const int GB = (NNODES + 63)/64;    // 782
  const int GE = (NEDGES + 255)/256;  // 3125

  // CSR build: LDS-privatized count (no global atomics) + scans + non-atomic place
  k_count<<<2*NPASS*NCH,1024,0,stream>>>(i_to, i_from, bhist2, elrank_to, elrank_from);
  k_scanA<<<2*NBLK,256,0,stream>>>(bhist2, bsum);
  k_scanBC<<<2*NBLK,256,0,stream>>>(bsum, bhist2, off_to, end_to, off_from, end_from,
                                    cbase, bhist, lrank_to, lrank_from);
  k_bscan<<<2,256,0,stream>>>(bhist, boff);
  k_dplace<<<NBLK,256,0,stream>>>(off_to, end_to, off_from, end_from, boff,
                                  lrank_to, lrank_from, perm_to, perm_from);
  k_place<<<GE,256,0,stream>>>(i_link, i_from, i_to, cbase, elrank_to, elrank_from,
                               pay_to, pay_from);

  // weight prepacks + node features
  k_prep_all<<<818,512,0,stream>>>(Wi, Wo, Wf, Wu, Wc, Wl, emb_link, bl,
                                   WgT, Wcfrag, Wlfrag, linkpart);
  k_ne<<<GB,256,0,stream>>>(i_token, emb_token, Wcfrag, bc, Wlfrag, npart);

  // x gathers (degree-sorted)
  k_gather_x<<<2*GN,256,0,stream>>>(off_to, end_to, pay_to, off_from, end_from, pay_from,
                                    perm_to, perm_from, linkpart, npart, xin, xout);

  // layer 1 fused (K=256 over x; f-gate skipped)
  k_gates<2><<<GB,256,0,stream>>>(xin, xout, nullptr, nullptr, WgT,
                                  bi, bo, bf_, bu, c1b, h1, nullptr);

  // h gathers (degree-sorted)
  k_gather_h<<<2*GN,256,0,stream>>>(off_to, end_to, pay_to, off_from, end_from, pay_from,
                                    perm_to, perm_from, h1, hin, houtb);

  // layer 2 fused (K=512)
  k_gates<4><<<GB,256,0,stream>>>(xin, xout, hin, houtb, WgT,
                                  bi, bo, bf_, bu, c1b, nullptr, out);
}

// Round 18
// 288.403 us; speedup vs baseline: 1.8558x; 1.0960x over previous
//
#include <hip/hip_runtime.h>
#include <math.h>

#define NNODES 50000
#define NEDGES 800000
#define NBLK 196    // ceil(50000/256)
#define GN 3125     // ceil(50000/16)
#define NPASS 4     // node-range passes (12500 nodes -> 50KB LDS hist)
#define PASSN 12500
#define NCH 16      // edge chunks
#define ECHUNK (NEDGES/NCH)   // 50000

typedef __attribute__((ext_vector_type(8))) short s16x8;
typedef __attribute__((ext_vector_type(8))) unsigned short u16x8;
typedef __attribute__((ext_vector_type(4))) unsigned short u16x4;
typedef __attribute__((ext_vector_type(4))) float f32x4;

#define TANH_C 2.885390081777927f   // 2*log2(e)

__device__ __forceinline__ float tanh_fast(float x){
  float e = __builtin_amdgcn_exp2f(x*TANH_C);
  return 1.0f - 2.0f*__builtin_amdgcn_rcpf(e+1.0f);
}
__device__ __forceinline__ float sig_fast(float x){
  float e = __builtin_amdgcn_exp2f(-1.4426950408889634f*x);
  return __builtin_amdgcn_rcpf(1.0f+e);
}
__device__ __forceinline__ unsigned short f2b(float f){
  union{float f; unsigned u;} v; v.f = f;
  unsigned r = (v.u + 0x7FFFu + ((v.u>>16)&1u)) >> 16;
  return (unsigned short)r;
}
__device__ __forceinline__ float b2f(unsigned short b){
  union{unsigned u; float f;} v; v.u = ((unsigned)b)<<16; return v.f;
}

// ---------- fused weight prep ----------
__global__ __launch_bounds__(512) void k_prep_all(
    const float* __restrict__ Wi, const float* __restrict__ Wo,
    const float* __restrict__ Wf, const float* __restrict__ Wu,
    const float* __restrict__ Wc, const float* __restrict__ Wl,
    const float* __restrict__ emb_link, const float* __restrict__ bl,
    unsigned short* __restrict__ Wfrag, unsigned short* __restrict__ Wcfrag,
    unsigned short* __restrict__ Wlfrag, unsigned short* __restrict__ lp){
  int b = blockIdx.x, t = threadIdx.x;
  if(b < 512){
    int n = b, k = t;
    const float* W = (n<128)? Wi : (n<256)? Wo : (n<384)? Wf : Wu;
    float v = W[(size_t)k*128 + (n&127)];
    int ks = k>>5, kb = (k>>3)&3, j = k&7;
    int nt = n>>4, lm = n&15;
    int l = lm + 16*kb;
    Wfrag[(size_t)(((ks*32 + nt)*64) + l)*8 + j] = f2b(v);
  } else if(b < 640){
    if(t < 320){
      int n = b-512, k = t;
      float v = (k < 300)? Wc[(size_t)k*128 + n] : 0.f;
      int ks = k>>5, kb = (k>>3)&3, j = k&7;
      int nt = n>>4, lm = n&15;
      int l = lm + 16*kb;
      Wcfrag[(size_t)(((ks*8 + nt)*64) + l)*8 + j] = f2b(v);
    }
  } else if(b < 768){
    if(t < 128){
      int n = b-640, k = t;
      float v = Wl[(size_t)(64+k)*128 + n];
      int ks = k>>5, kb = (k>>3)&3, j = k&7;
      int nt = n>>4, lm = n&15;
      int l = lm + 16*kb;
      Wlfrag[(size_t)(((ks*8 + nt)*64) + l)*8 + j] = f2b(v);
    }
  } else {
    if(t < 128){
      int l = b-768, d = t;
      float acc = bl[d];
      #pragma unroll 8
      for(int k=0;k<64;k++) acc += emb_link[l*64+k]*Wl[k*128+d];
      lp[l*128+d] = f2b(acc*TANH_C);       // pre-scaled for gather tanh
    }
  }
}

// Fused: E1 = tanh(gather(emb_token)@Wc + bc); npart = bf16(TANH_C * (E1 @ Wl[64:192]))
__global__ __launch_bounds__(256,2) void k_ne(const int* __restrict__ i_token,
      const float* __restrict__ emb_token, const unsigned short* __restrict__ Wcfrag,
      const float* __restrict__ bc, const unsigned short* __restrict__ Wlfrag,
      unsigned short* __restrict__ npart){
  __shared__ unsigned short As[64*36];
  __shared__ unsigned short E1[64*132];
  __shared__ int rowidx[64];
  int t = threadIdx.x;
  int m0 = blockIdx.x*64;
  if(t<64){ int m=m0+t; rowidx[t]=(m<NNODES)? i_token[m]:0; }
  int w=t>>6, l=t&63, lm=l&15, kb=l>>4;
  f32x4 acc[2][4];
  #pragma unroll
  for(int c=0;c<2;c++)
    #pragma unroll
    for(int r=0;r<4;r++) acc[c][r]=(f32x4){0.f,0.f,0.f,0.f};
  int sr=t>>2, sp=t&3;
  __syncthreads();
  const float* srcrow = emb_token + (size_t)rowidx[sr]*300;
  for(int ks=0; ks<10; ks++){
    int k0 = ks*32 + sp*8;
    u16x8 v;
    #pragma unroll
    for(int j=0;j<8;j++){ int k=k0+j; v[j] = (k<300)? f2b(srcrow[k]) : (unsigned short)0; }
    if(ks) __syncthreads();
    *(u16x8*)(As + sr*36 + sp*8) = v;
    __syncthreads();
    s16x8 af[4];
    #pragma unroll
    for(int rt=0;rt<4;rt++) af[rt] = *(const s16x8*)(As + (16*rt+lm)*36 + kb*8);
    #pragma unroll
    for(int c=0;c<2;c++){
      int nt = 2*w + c;
      s16x8 bfr = *(const s16x8*)(Wcfrag + (size_t)((ks*8+nt)*64 + l)*8);
      #pragma unroll
      for(int rt=0;rt<4;rt++)
        acc[c][rt] = __builtin_amdgcn_mfma_f32_16x16x32_bf16(af[rt], bfr, acc[c][rt],0,0,0);
    }
  }
  __syncthreads();
  #pragma unroll
  for(int c=0;c<2;c++){
    int d = 16*(2*w+c) + lm;
    float vb = bc[d];
    #pragma unroll
    for(int rt=0;rt<4;rt++)
      #pragma unroll
      for(int reg=0;reg<4;reg++){
        int r = 16*rt + kb*4 + reg;
        E1[r*132 + d] = f2b(tanh_fast(acc[c][rt][reg]+vb));
      }
  }
  __syncthreads();
  f32x4 acc2[2][4];
  #pragma unroll
  for(int c=0;c<2;c++)
    #pragma unroll
    for(int r=0;r<4;r++) acc2[c][r]=(f32x4){0.f,0.f,0.f,0.f};
  #pragma unroll
  for(int ks=0; ks<4; ks++){
    s16x8 af[4];
    #pragma unroll
    for(int rt=0;rt<4;rt++) af[rt] = *(const s16x8*)(E1 + (16*rt+lm)*132 + ks*32 + kb*8);
    #pragma unroll
    for(int c=0;c<2;c++){
      int nt = 2*w + c;
      s16x8 bfr = *(const s16x8*)(Wlfrag + (size_t)((ks*8+nt)*64 + l)*8);
      #pragma unroll
      for(int rt=0;rt<4;rt++)
        acc2[c][rt] = __builtin_amdgcn_mfma_f32_16x16x32_bf16(af[rt], bfr, acc2[c][rt],0,0,0);
    }
  }
  #pragma unroll
  for(int c=0;c<2;c++){
    int d = 16*(2*w+c) + lm;
    #pragma unroll
    for(int rt=0;rt<4;rt++)
      #pragma unroll
      for(int reg=0;reg<4;reg++){
        int m = m0 + 16*rt + kb*4 + reg;
        if(m < NNODES) npart[(size_t)m*128 + d] = f2b(acc2[c][rt][reg]*TANH_C);
      }
  }
}

// ---------------- CSR build: LDS-privatized chunked counting sort ----------------
__global__ __launch_bounds__(1024) void k_count(const int* __restrict__ i_to,
      const int* __restrict__ i_from, int* __restrict__ bhist2,
      int* __restrict__ elrank_to, int* __restrict__ elrank_from){
  __shared__ int hist[PASSN];
  int b = blockIdx.x;
  int dir = b / (NPASS*NCH);
  int rem = b - dir*(NPASS*NCH);
  int p = rem / NCH, ch = rem - p*NCH;
  const int* ids = dir ? i_from : i_to;
  int* elrank = dir ? elrank_from : elrank_to;
  int t = threadIdx.x;
  for(int i=t;i<PASSN;i+=1024) hist[i]=0;
  __syncthreads();
  int base = ch*ECHUNK;
  for(int e=base+t; e<base+ECHUNK; e+=1024){
    int r = ids[e] - p*PASSN;
    if((unsigned)r < PASSN) elrank[e] = atomicAdd(&hist[r],1);
  }
  __syncthreads();
  int* dst = bhist2 + (size_t)b*PASSN;
  for(int i=t;i<PASSN;i+=1024) dst[i]=hist[i];
}

__global__ __launch_bounds__(256) void k_scanA(const int* __restrict__ bhist2,
      int* __restrict__ bsum){
  int b = blockIdx.x; int dir = (b >= NBLK); int bb = dir? b-NBLK : b;
  int t = threadIdx.x;
  int idx = bb*256 + t;
  int c = 0;
  if(idx < NNODES){
    int p = idx/PASSN, ln = idx - p*PASSN;
    const int* src = bhist2 + (size_t)(dir*NPASS*NCH + p*NCH)*PASSN + ln;
    #pragma unroll
    for(int ch=0;ch<NCH;ch++) c += src[ch*PASSN];
  }
  __shared__ int red[256];
  red[t] = c; __syncthreads();
  for(int s=128;s>0;s>>=1){ if(t<s) red[t]+=red[t+s]; __syncthreads(); }
  if(t==0) bsum[b] = red[0];
}

__global__ __launch_bounds__(256) void k_scanBC(const int* __restrict__ bsum,
      const int* __restrict__ bhist2,
      int* __restrict__ off_to, int* __restrict__ end_to,
      int* __restrict__ off_from, int* __restrict__ end_from,
      int* __restrict__ cbase,
      int* __restrict__ bhist, int* __restrict__ lrank_to, int* __restrict__ lrank_from){
  int b = blockIdx.x; int dir = (b >= NBLK); int bb = dir? b-NBLK : b;
  int* off = dir? off_from : off_to;
  int* end = dir? end_from : end_to;
  int* lrank = dir? lrank_from : lrank_to;
  __shared__ int sh[256];
  __shared__ int hist[64];
  int t = threadIdx.x;
  sh[t] = (t < NBLK)? bsum[dir*NBLK + t] : 0;
  if(t < 64) hist[t] = 0;
  __syncthreads();
  for(int d=1; d<256; d<<=1){
    int v = (t>=d)? sh[t-d] : 0;
    __syncthreads(); sh[t] += v; __syncthreads();
  }
  int bpre = (bb==0)? 0 : sh[bb-1];
  __syncthreads();
  int idx = bb*256 + t;
  int vals[NCH];
  int c = 0;
  if(idx < NNODES){
    int p = idx/PASSN, ln = idx - p*PASSN;
    const int* src = bhist2 + (size_t)(dir*NPASS*NCH + p*NCH)*PASSN + ln;
    #pragma unroll
    for(int ch=0;ch<NCH;ch++){ vals[ch] = src[ch*PASSN]; c += vals[ch]; }
  }
  sh[t] = c; __syncthreads();
  for(int d=1; d<256; d<<=1){
    int v = (t>=d)? sh[t-d] : 0;
    __syncthreads(); sh[t] += v; __syncthreads();
  }
  if(idx < NNODES){
    int o = bpre + ((t==0)? 0 : sh[t-1]);
    off[idx] = o;
    end[idx] = o + c;
    int run = o;
    #pragma unroll
    for(int ch=0;ch<NCH;ch++){
      cbase[(size_t)(dir*NCH + ch)*NNODES + idx] = run;
      run += vals[ch];
    }
    lrank[idx] = atomicAdd(&hist[min(c,63)], 1);
  }
  __syncthreads();
  if(t < 64) bhist[dir*64*NBLK + t*NBLK + bb] = hist[t];
}

__global__ __launch_bounds__(256) void k_bscan(const int* __restrict__ bhist, int* __restrict__ boff){
  const int N = 64*NBLK;
  const int CH = (N+255)/256;
  int dir = blockIdx.x;
  __shared__ int part[256];
  int t = threadIdx.x;
  int base = t*CH;
  int s = 0;
  for(int i=0;i<CH;i++){ int id=base+i; if(id<N) s += bhist[dir*N+id]; }
  part[t] = s; __syncthreads();
  for(int d=1; d<256; d<<=1){
    int v = (t>=d)? part[t-d] : 0;
    __syncthreads(); part[t] += v; __syncthreads();
  }
  int run = (t==0)? 0 : part[t-1];
  for(int i=0;i<CH;i++){
    int id = base+i;
    if(id<N){ boff[dir*N+id] = run; run += bhist[dir*N+id]; }
  }
}

__global__ void k_dplace(const int* __restrict__ off_to, const int* __restrict__ end_to,
                         const int* __restrict__ off_from, const int* __restrict__ end_from,
                         const int* __restrict__ boff,
                         const int* __restrict__ lrank_to, const int* __restrict__ lrank_from,
                         int* __restrict__ perm_to, int* __restrict__ perm_from){
  int idx = blockIdx.x*256 + threadIdx.x;
  if(idx >= NNODES) return;
  int blk = idx >> 8;
  int d1 = end_to[idx]-off_to[idx];
  perm_to[ boff[min(d1,63)*NBLK + blk] + lrank_to[idx] ] = idx;
  int d2 = end_from[idx]-off_from[idx];
  perm_from[ boff[64*NBLK + min(d2,63)*NBLK + blk] + lrank_from[idx] ] = idx;
}

__global__ void k_place(const int* __restrict__ i_link, const int* __restrict__ i_from,
                        const int* __restrict__ i_to,
                        const int* __restrict__ cbase,
                        const int* __restrict__ elrank_to, const int* __restrict__ elrank_from,
                        int* __restrict__ pay_to, int* __restrict__ pay_from){
  int e = blockIdx.x*256 + threadIdx.x;
  if(e >= NEDGES) return;
  int il = i_link[e], f = i_from[e], tt = i_to[e];
  int ch = e / ECHUNK;
  pay_to  [ cbase[(size_t)ch*NNODES + tt]            + elrank_to[e] ]   = f  | (il<<16);
  pay_from[ cbase[(size_t)(NCH+ch)*NNODES + f]       + elrank_from[e] ] = tt | (il<<16);
}

// ---------------- gathers (16 lanes/node, degree-sorted, 2x unrolled) ----------------
__global__ __launch_bounds__(256) void k_gather_x(
      const int* __restrict__ off_to, const int* __restrict__ end_to, const int* __restrict__ pay_to,
      const int* __restrict__ off_from, const int* __restrict__ end_from, const int* __restrict__ pay_from,
      const int* __restrict__ perm_to, const int* __restrict__ perm_from,
      const unsigned short* __restrict__ lp, const unsigned short* __restrict__ npart,
      unsigned short* __restrict__ xin, unsigned short* __restrict__ xout){
  int isOut = (blockIdx.x >= GN);
  int bb = isOut? blockIdx.x-GN : blockIdx.x;
  int slot = bb*16 + (threadIdx.x>>4);
  int n = isOut? perm_from[slot] : perm_to[slot];
  int c = (threadIdx.x & 15)*8;
  const int* off = isOut? off_from : off_to;
  const int* end = isOut? end_from : end_to;
  const int* pay = isOut? pay_from : pay_to;
  unsigned short* out = isOut? xout : xin;
  float acc[8];
  #pragma unroll
  for(int q=0;q<8;q++) acc[q]=0.f;
  int s = off[n], e = end[n];
  if(isOut){
    u16x8 bb8 = *(const u16x8*)(npart + (size_t)n*128 + c);
    float bf[8];
    #pragma unroll
    for(int q=0;q<8;q++) bf[q]=b2f(bb8[q]);
    int j = s;
    for(; j+1<e; j+=2){
      int p0 = pay[j], p1 = pay[j+1];
      u16x8 a0 = *(const u16x8*)(lp + (p0>>16)*128 + c);
      u16x8 a1 = *(const u16x8*)(lp + (p1>>16)*128 + c);
      #pragma unroll
      for(int q=0;q<8;q++){
        float e0 = __builtin_amdgcn_exp2f(b2f(a0[q])+bf[q]);
        float e1 = __builtin_amdgcn_exp2f(b2f(a1[q])+bf[q]);
        acc[q] += __builtin_amdgcn_rcpf(e0+1.0f) + __builtin_amdgcn_rcpf(e1+1.0f);
      }
    }
    if(j<e){
      int p0 = pay[j];
      u16x8 a0 = *(const u16x8*)(lp + (p0>>16)*128 + c);
      #pragma unroll
      for(int q=0;q<8;q++){
        float e0 = __builtin_amdgcn_exp2f(b2f(a0[q])+bf[q]);
        acc[q] += __builtin_amdgcn_rcpf(e0+1.0f);
      }
    }
  } else {
    int j = s;
    for(; j+1<e; j+=2){
      int p0 = pay[j], p1 = pay[j+1];
      u16x8 a0 = *(const u16x8*)(lp + (p0>>16)*128 + c);
      u16x8 b0 = *(const u16x8*)(npart + (size_t)(p0&0xFFFF)*128 + c);
      u16x8 a1 = *(const u16x8*)(lp + (p1>>16)*128 + c);
      u16x8 b1 = *(const u16x8*)(npart + (size_t)(p1&0xFFFF)*128 + c);
      #pragma unroll
      for(int q=0;q<8;q++){
        float e0 = __builtin_amdgcn_exp2f(b2f(a0[q])+b2f(b0[q]));
        float e1 = __builtin_amdgcn_exp2f(b2f(a1[q])+b2f(b1[q]));
        acc[q] += __builtin_amdgcn_rcpf(e0+1.0f) + __builtin_amdgcn_rcpf(e1+1.0f);
      }
    }
    if(j<e){
      int p0 = pay[j];
      u16x8 a0 = *(const u16x8*)(lp + (p0>>16)*128 + c);
      u16x8 b0 = *(const u16x8*)(npart + (size_t)(p0&0xFFFF)*128 + c);
      #pragma unroll
      for(int q=0;q<8;q++){
        float e0 = __builtin_amdgcn_exp2f(b2f(a0[q])+b2f(b0[q]));
        acc[q] += __builtin_amdgcn_rcpf(e0+1.0f);
      }
    }
  }
  float deg = (float)(e - s);
  u16x8 o;
  #pragma unroll
  for(int q=0;q<8;q++) o[q]=f2b(deg - 2.0f*acc[q]);
  *(u16x8*)(out + (size_t)n*128 + c) = o;
}

__global__ __launch_bounds__(256) void k_gather_h(
      const int* __restrict__ off_to, const int* __restrict__ end_to, const int* __restrict__ pay_to,
      const int* __restrict__ off_from, const int* __restrict__ end_from, const int* __restrict__ pay_from,
      const int* __restrict__ perm_to, const int* __restrict__ perm_from,
      const unsigned short* __restrict__ src, unsigned short* __restrict__ hin,
      unsigned short* __restrict__ hout){
  int isOut = (blockIdx.x >= GN);
  int bb = isOut? blockIdx.x-GN : blockIdx.x;
  int slot = bb*16 + (threadIdx.x>>4);
  int n = isOut? perm_from[slot] : perm_to[slot];
  int c = (threadIdx.x & 15)*8;
  const int* off = isOut? off_from : off_to;
  const int* end = isOut? end_from : end_to;
  const int* pay = isOut? pay_from : pay_to;
  unsigned short* out = isOut? hout : hin;
  float acc[8];
  #pragma unroll
  for(int q=0;q<8;q++) acc[q]=0.f;
  int s = off[n], e = end[n];
  int j = s;
  for(; j+1<e; j+=2){
    int v0 = pay[j] & 0xFFFF, v1 = pay[j+1] & 0xFFFF;
    u16x8 a0 = *(const u16x8*)(src + (size_t)v0*128 + c);
    u16x8 a1 = *(const u16x8*)(src + (size_t)v1*128 + c);
    #pragma unroll
    for(int q=0;q<8;q++) acc[q] += b2f(a0[q]) + b2f(a1[q]);
  }
  if(j<e){
    int v0 = pay[j] & 0xFFFF;
    u16x8 a0 = *(const u16x8*)(src + (size_t)v0*128 + c);
    #pragma unroll
    for(int q=0;q<8;q++) acc[q] += b2f(a0[q]);
  }
  u16x8 o;
  #pragma unroll
  for(int q=0;q<8;q++) o[q]=f2b(acc[q]);
  *(u16x8*)(out + (size_t)n*128 + c) = o;
}

// ---------------- fused MFMA gate GEMM + LSTM cell ----------------
// 8 waves x 512 threads: wave q owns col-tile d in [16q,16q+16), all 4 gates.
// acc = 64 VGPR/wave -> more resident waves; LDS A-staging + reg-prefetch pipeline.
template<int P>
__device__ __forceinline__ const unsigned short* pick(
    const unsigned short* x0, const unsigned short* x1,
    const unsigned short* x2, const unsigned short* x3, int ks){
  if(P==2) return (ks<4)? x0 : x1;
  return (ks<4)? x0 : (ks<8)? x1 : (ks<12)? x2 : x3;
}

template<int P>
__global__ __launch_bounds__(512,2) void k_gates(
    const unsigned short* __restrict__ x0, const unsigned short* __restrict__ x1,
    const unsigned short* __restrict__ x2, const unsigned short* __restrict__ x3,
    const unsigned short* __restrict__ Wfrag,
    const float* __restrict__ bi, const float* __restrict__ bo,
    const float* __restrict__ bfg, const float* __restrict__ bu,
    unsigned short* __restrict__ c1b, unsigned short* __restrict__ h1,
    float* __restrict__ hout)
{
  __shared__ unsigned short As[2][64*36];
  int t = threadIdx.x;
  int m0 = blockIdx.x*64;
  int q = t>>6;              // wave id = output col-tile
  int l = t&63;
  int lm = l&15, kb = l>>4;
  f32x4 acc[4][4];           // [gate][rowtile]
  #pragma unroll
  for(int g=0;g<4;g++)
    #pragma unroll
    for(int r=0;r<4;r++) acc[g][r]=(f32x4){0.f,0.f,0.f,0.f};
  // A staging: 512 threads cover 64 rows x 32 k as 8B (u16x4) chunks
  int sr = t>>3, sp = t&7;
  int sm = m0 + sr; if(sm >= NNODES) sm = NNODES-1;
  size_t soff = (size_t)sm*128 + sp*4;
  const int KSTEPS = P*4;
  u16x4 v0 = *(const u16x4*)(pick<P>(x0,x1,x2,x3,0) + soff + 0);
  *(u16x4*)(As[0] + sr*36 + sp*4) = v0;
  u16x4 vn = *(const u16x4*)(pick<P>(x0,x1,x2,x3,1) + soff + 32);
  __syncthreads();
  #pragma unroll
  for(int ks=0; ks<KSTEPS; ks++){
    int cur = ks&1;
    if(ks+1 < KSTEPS) *(u16x4*)(As[cur^1] + sr*36 + sp*4) = vn;
    if(ks+2 < KSTEPS)
      vn = *(const u16x4*)(pick<P>(x0,x1,x2,x3,ks+2) + soff + ((ks+2)&3)*32);
    s16x8 af[4];
    #pragma unroll
    for(int rt=0; rt<4; rt++)
      af[rt] = *(const s16x8*)(As[cur] + (16*rt+lm)*36 + kb*8);
    #pragma unroll
    for(int g=0;g<4;g++){
      if(P==2 && g==2) continue;     // layer 1: f-gate unused (c_prev = 0)
      int nt = 8*g + q;
      s16x8 bfr = *(const s16x8*)(Wfrag + (size_t)((ks*32 + nt)*64 + l)*8);
      #pragma unroll
      for(int rt=0; rt<4; rt++)
        acc[g][rt] = __builtin_amdgcn_mfma_f32_16x16x32_bf16(af[rt], bfr, acc[g][rt], 0,0,0);
    }
    __syncthreads();
  }
  int d = 16*q + lm;
  float vbi = bi[d], vbo = bo[d], vbu = bu[d];
  float vbf = (P==4)? bfg[d] : 0.f;
  #pragma unroll
  for(int rt=0; rt<4; rt++){
    #pragma unroll
    for(int reg=0; reg<4; reg++){
      int m = m0 + 16*rt + kb*4 + reg;
      if(m < NNODES){
        size_t o = (size_t)m*128 + d;
        float pi = acc[0][rt][reg] + vbi;
        float po = acc[1][rt][reg] + vbo;
        float pu = acc[3][rt][reg] + vbu;
        if(P==2){
          float c1v = sig_fast(pi)*tanh_fast(pu);
          float hv  = sig_fast(po)*tanh_fast(c1v);
          c1b[o] = f2b(c1v);
          h1[o] = f2b(hv);
        } else {
          float pf = acc[2][rt][reg] + vbf;
          float c2 = sig_fast(pf)*b2f(c1b[o]) + sig_fast(pi)*tanh_fast(pu);
          hout[o] = sig_fast(po)*tanh_fast(c2);
        }
      }
    }
  }
}

extern "C" void kernel_launch(void* const* d_in, const int* in_sizes, int n_in,
                              void* d_out, int out_size, void* d_ws, size_t ws_size,
                              hipStream_t stream){
  const int*   i_token  = (const int*)d_in[0];
  const int*   i_link   = (const int*)d_in[1];
  const int*   i_from   = (const int*)d_in[2];
  const int*   i_to     = (const int*)d_in[3];
  const float* emb_token= (const float*)d_in[4];
  const float* emb_link = (const float*)d_in[5];
  const float* Wc = (const float*)d_in[6];  const float* bc = (const float*)d_in[7];
  const float* Wl = (const float*)d_in[8];  const float* bl = (const float*)d_in[9];
  const float* Wi = (const float*)d_in[10]; const float* bi = (const float*)d_in[11];
  const float* Wo = (const float*)d_in[12]; const float* bo = (const float*)d_in[13];
  const float* Wf = (const float*)d_in[14]; const float* bf_ = (const float*)d_in[15];
  const float* Wu = (const float*)d_in[16]; const float* bu = (const float*)d_in[17];
  float* out = (float*)d_out;

  const size_t NB = (size_t)NNODES*128;
  unsigned short* c1b   = (unsigned short*)d_ws;
  unsigned short* npart = c1b + NB;
  unsigned short* xin   = npart + NB;
  unsigned short* xout  = xin + NB;
  unsigned short* hin   = xout + NB;
  unsigned short* houtb = hin + NB;
  unsigned short* h1    = houtb + NB;
  unsigned short* WgT   = h1 + NB;
  unsigned short* Wcfrag = WgT + 512*512;
  unsigned short* Wlfrag = Wcfrag + 320*128;
  unsigned short* linkpart = Wlfrag + 128*128;
  int* ia = (int*)(linkpart + 50*128);
  int* bhist2   = ia;                             // 2*NPASS*NCH*PASSN
  int* cbase    = bhist2 + 2*NPASS*NCH*PASSN;     // 2*NCH*NNODES
  int* off_to   = cbase + 2*NCH*NNODES;
  int* end_to   = off_to + NNODES;
  int* off_from = end_to + NNODES;
  int* end_from = off_from + NNODES;
  int* lrank_to = end_from + NNODES;
  int* lrank_from = lrank_to + NNODES;
  int* perm_to  = lrank_from + NNODES;
  int* perm_from= perm_to + NNODES;
  int* bsum     = perm_from + NNODES;             // 2*NBLK
  int* bhist    = bsum + 2*NBLK;                  // 2*64*NBLK
  int* boff     = bhist + 2*64*NBLK;              // 2*64*NBLK
  int* pay_to   = boff + 2*64*NBLK;
  int* pay_from = pay_to + NEDGES;
  int* elrank_to  = pay_from + NEDGES;
  int* elrank_from= elrank_to + NEDGES;

  const int GB = (NNODES + 63)/64;    // 782
  const int GE = (NEDGES + 255)/256;  // 3125

  // CSR build: LDS-privatized count (no global atomics) + scans + non-atomic place
  k_count<<<2*NPASS*NCH,1024,0,stream>>>(i_to, i_from, bhist2, elrank_to, elrank_from);
  k_scanA<<<2*NBLK,256,0,stream>>>(bhist2, bsum);
  k_scanBC<<<2*NBLK,256,0,stream>>>(bsum, bhist2, off_to, end_to, off_from, end_from,
                                    cbase, bhist, lrank_to, lrank_from);
  k_bscan<<<2,256,0,stream>>>(bhist, boff);
  k_dplace<<<NBLK,256,0,stream>>>(off_to, end_to, off_from, end_from, boff,
                                  lrank_to, lrank_from, perm_to, perm_from);
  k_place<<<GE,256,0,stream>>>(i_link, i_from, i_to, cbase, elrank_to, elrank_from,
                               pay_to, pay_from);

  // weight prepacks + node features
  k_prep_all<<<818,512,0,stream>>>(Wi, Wo, Wf, Wu, Wc, Wl, emb_link, bl,
                                   WgT, Wcfrag, Wlfrag, linkpart);
  k_ne<<<GB,256,0,stream>>>(i_token, emb_token, Wcfrag, bc, Wlfrag, npart);

  // x gathers (degree-sorted)
  k_gather_x<<<2*GN,256,0,stream>>>(off_to, end_to, pay_to, off_from, end_from, pay_from,
                                    perm_to, perm_from, linkpart, npart, xin, xout);

  // layer 1 fused (K=256 over x; f-gate skipped)
  k_gates<2><<<GB,512,0,stream>>>(xin, xout, nullptr, nullptr, WgT,
                                  bi, bo, bf_, bu, c1b, h1, nullptr);

  // h gathers (degree-sorted)
  k_gather_h<<<2*GN,256,0,stream>>>(off_to, end_to, pay_to, off_from, end_from, pay_from,
                                    perm_to, perm_from, h1, hin, houtb);

  // layer 2 fused (K=512)
  k_gates<4><<<GB,512,0,stream>>>(xin, xout, hin, houtb, WgT,
                                  bi, bo, bf_, bu, c1b, nullptr, out);
}

// Round 20
// 277.270 us; speedup vs baseline: 1.9304x; 1.0402x over previous
//
#include <hip/hip_runtime.h>
#include <math.h>

#define NNODES 50000
#define NEDGES 800000
#define NBLK 196    // ceil(50000/256)
#define GN 3125     // ceil(50000/16)
#define NPASS 4     // node-range passes (12500 nodes -> 50KB LDS hist)
#define PASSN 12500
#define NCH 16      // edge chunks
#define ECHUNK (NEDGES/NCH)   // 50000

typedef __attribute__((ext_vector_type(8))) short s16x8;
typedef __attribute__((ext_vector_type(8))) unsigned short u16x8;
typedef __attribute__((ext_vector_type(4))) unsigned short u16x4;
typedef __attribute__((ext_vector_type(4))) float f32x4;

#define TANH_C 2.885390081777927f   // 2*log2(e)

__device__ __forceinline__ float tanh_fast(float x){
  float e = __builtin_amdgcn_exp2f(x*TANH_C);
  return 1.0f - 2.0f*__builtin_amdgcn_rcpf(e+1.0f);
}
__device__ __forceinline__ float sig_fast(float x){
  float e = __builtin_amdgcn_exp2f(-1.4426950408889634f*x);
  return __builtin_amdgcn_rcpf(1.0f+e);
}
__device__ __forceinline__ unsigned short f2b(float f){
  union{float f; unsigned u;} v; v.f = f;
  unsigned r = (v.u + 0x7FFFu + ((v.u>>16)&1u)) >> 16;
  return (unsigned short)r;
}
__device__ __forceinline__ float b2f(unsigned short b){
  union{unsigned u; float f;} v; v.u = ((unsigned)b)<<16; return v.f;
}
// fp16 encode/decode (for exp-domain tables: 10-bit mantissa; inf/0 saturate correctly)
__device__ __forceinline__ unsigned short f2h(float f){
  _Float16 h = (_Float16)f;
  return __builtin_bit_cast(unsigned short, h);
}
__device__ __forceinline__ float h2f(unsigned short b){
  return (float)__builtin_bit_cast(_Float16, b);
}

// ---------- fused weight prep ----------
// lp stores E_lp = fp16(exp2(TANH_C * linkpart))   (exponential-domain)
__global__ __launch_bounds__(512) void k_prep_all(
    const float* __restrict__ Wi, const float* __restrict__ Wo,
    const float* __restrict__ Wf, const float* __restrict__ Wu,
    const float* __restrict__ Wc, const float* __restrict__ Wl,
    const float* __restrict__ emb_link, const float* __restrict__ bl,
    unsigned short* __restrict__ Wfrag, unsigned short* __restrict__ Wcfrag,
    unsigned short* __restrict__ Wlfrag, unsigned short* __restrict__ lp){
  int b = blockIdx.x, t = threadIdx.x;
  if(b < 512){
    int n = b, k = t;
    const float* W = (n<128)? Wi : (n<256)? Wo : (n<384)? Wf : Wu;
    float v = W[(size_t)k*128 + (n&127)];
    int ks = k>>5, kb = (k>>3)&3, j = k&7;
    int nt = n>>4, lm = n&15;
    int l = lm + 16*kb;
    Wfrag[(size_t)(((ks*32 + nt)*64) + l)*8 + j] = f2b(v);
  } else if(b < 640){
    if(t < 320){
      int n = b-512, k = t;
      float v = (k < 300)? Wc[(size_t)k*128 + n] : 0.f;
      int ks = k>>5, kb = (k>>3)&3, j = k&7;
      int nt = n>>4, lm = n&15;
      int l = lm + 16*kb;
      Wcfrag[(size_t)(((ks*8 + nt)*64) + l)*8 + j] = f2b(v);
    }
  } else if(b < 768){
    if(t < 128){
      int n = b-640, k = t;
      float v = Wl[(size_t)(64+k)*128 + n];
      int ks = k>>5, kb = (k>>3)&3, j = k&7;
      int nt = n>>4, lm = n&15;
      int l = lm + 16*kb;
      Wlfrag[(size_t)(((ks*8 + nt)*64) + l)*8 + j] = f2b(v);
    }
  } else {
    if(t < 128){
      int l = b-768, d = t;
      float acc = bl[d];
      #pragma unroll 8
      for(int k=0;k<64;k++) acc += emb_link[l*64+k]*Wl[k*128+d];
      lp[l*128+d] = f2h(__builtin_amdgcn_exp2f(acc*TANH_C));   // E_lp (fp16)
    }
  }
}

// Fused: E1 = tanh(gather(emb_token)@Wc + bc); E_np = fp16(exp2(TANH_C*(E1@Wl[64:192])))
__global__ __launch_bounds__(256,2) void k_ne(const int* __restrict__ i_token,
      const float* __restrict__ emb_token, const unsigned short* __restrict__ Wcfrag,
      const float* __restrict__ bc, const unsigned short* __restrict__ Wlfrag,
      unsigned short* __restrict__ npart){
  __shared__ unsigned short As[64*36];
  __shared__ unsigned short E1[64*132];
  __shared__ int rowidx[64];
  int t = threadIdx.x;
  int m0 = blockIdx.x*64;
  if(t<64){ int m=m0+t; rowidx[t]=(m<NNODES)? i_token[m]:0; }
  int w=t>>6, l=t&63, lm=l&15, kb=l>>4;
  f32x4 acc[2][4];
  #pragma unroll
  for(int c=0;c<2;c++)
    #pragma unroll
    for(int r=0;r<4;r++) acc[c][r]=(f32x4){0.f,0.f,0.f,0.f};
  int sr=t>>2, sp=t&3;
  __syncthreads();
  const float* srcrow = emb_token + (size_t)rowidx[sr]*300;
  for(int ks=0; ks<10; ks++){
    int k0 = ks*32 + sp*8;
    u16x8 v;
    #pragma unroll
    for(int j=0;j<8;j++){ int k=k0+j; v[j] = (k<300)? f2b(srcrow[k]) : (unsigned short)0; }
    if(ks) __syncthreads();
    *(u16x8*)(As + sr*36 + sp*8) = v;
    __syncthreads();
    s16x8 af[4];
    #pragma unroll
    for(int rt=0;rt<4;rt++) af[rt] = *(const s16x8*)(As + (16*rt+lm)*36 + kb*8);
    #pragma unroll
    for(int c=0;c<2;c++){
      int nt = 2*w + c;
      s16x8 bfr = *(const s16x8*)(Wcfrag + (size_t)((ks*8+nt)*64 + l)*8);
      #pragma unroll
      for(int rt=0;rt<4;rt++)
        acc[c][rt] = __builtin_amdgcn_mfma_f32_16x16x32_bf16(af[rt], bfr, acc[c][rt],0,0,0);
    }
  }
  __syncthreads();
  #pragma unroll
  for(int c=0;c<2;c++){
    int d = 16*(2*w+c) + lm;
    float vb = bc[d];
    #pragma unroll
    for(int rt=0;rt<4;rt++)
      #pragma unroll
      for(int reg=0;reg<4;reg++){
        int r = 16*rt + kb*4 + reg;
        E1[r*132 + d] = f2b(tanh_fast(acc[c][rt][reg]+vb));
      }
  }
  __syncthreads();
  f32x4 acc2[2][4];
  #pragma unroll
  for(int c=0;c<2;c++)
    #pragma unroll
    for(int r=0;r<4;r++) acc2[c][r]=(f32x4){0.f,0.f,0.f,0.f};
  #pragma unroll
  for(int ks=0; ks<4; ks++){
    s16x8 af[4];
    #pragma unroll
    for(int rt=0;rt<4;rt++) af[rt] = *(const s16x8*)(E1 + (16*rt+lm)*132 + ks*32 + kb*8);
    #pragma unroll
    for(int c=0;c<2;c++){
      int nt = 2*w + c;
      s16x8 bfr = *(const s16x8*)(Wlfrag + (size_t)((ks*8+nt)*64 + l)*8);
      #pragma unroll
      for(int rt=0;rt<4;rt++)
        acc2[c][rt] = __builtin_amdgcn_mfma_f32_16x16x32_bf16(af[rt], bfr, acc2[c][rt],0,0,0);
    }
  }
  #pragma unroll
  for(int c=0;c<2;c++){
    int d = 16*(2*w+c) + lm;
    #pragma unroll
    for(int rt=0;rt<4;rt++)
      #pragma unroll
      for(int reg=0;reg<4;reg++){
        int m = m0 + 16*rt + kb*4 + reg;
        if(m < NNODES)
          npart[(size_t)m*128 + d] = f2h(__builtin_amdgcn_exp2f(acc2[c][rt][reg]*TANH_C)); // E_np (fp16)
      }
  }
}

// ---------------- CSR build: LDS-privatized chunked counting sort ----------------
__global__ __launch_bounds__(1024) void k_count(const int* __restrict__ i_to,
      const int* __restrict__ i_from, int* __restrict__ bhist2,
      int* __restrict__ elrank_to, int* __restrict__ elrank_from){
  __shared__ int hist[PASSN];
  int b = blockIdx.x;
  int dir = b / (NPASS*NCH);
  int rem = b - dir*(NPASS*NCH);
  int p = rem / NCH, ch = rem - p*NCH;
  const int* ids = dir ? i_from : i_to;
  int* elrank = dir ? elrank_from : elrank_to;
  int t = threadIdx.x;
  for(int i=t;i<PASSN;i+=1024) hist[i]=0;
  __syncthreads();
  int base = ch*ECHUNK;
  for(int e=base+t; e<base+ECHUNK; e+=1024){
    int r = ids[e] - p*PASSN;
    if((unsigned)r < PASSN) elrank[e] = atomicAdd(&hist[r],1);
  }
  __syncthreads();
  int* dst = bhist2 + (size_t)b*PASSN;
  for(int i=t;i<PASSN;i+=1024) dst[i]=hist[i];
}

__global__ __launch_bounds__(256) void k_scanA(const int* __restrict__ bhist2,
      int* __restrict__ bsum){
  int b = blockIdx.x; int dir = (b >= NBLK); int bb = dir? b-NBLK : b;
  int t = threadIdx.x;
  int idx = bb*256 + t;
  int c = 0;
  if(idx < NNODES){
    int p = idx/PASSN, ln = idx - p*PASSN;
    const int* src = bhist2 + (size_t)(dir*NPASS*NCH + p*NCH)*PASSN + ln;
    #pragma unroll
    for(int ch=0;ch<NCH;ch++) c += src[ch*PASSN];
  }
  __shared__ int red[256];
  red[t] = c; __syncthreads();
  for(int s=128;s>0;s>>=1){ if(t<s) red[t]+=red[t+s]; __syncthreads(); }
  if(t==0) bsum[b] = red[0];
}

__global__ __launch_bounds__(256) void k_scanBC(const int* __restrict__ bsum,
      const int* __restrict__ bhist2,
      int* __restrict__ off_to, int* __restrict__ end_to,
      int* __restrict__ off_from, int* __restrict__ end_from,
      int* __restrict__ cbase,
      int* __restrict__ bhist, int* __restrict__ lrank_to, int* __restrict__ lrank_from){
  int b = blockIdx.x; int dir = (b >= NBLK); int bb = dir? b-NBLK : b;
  int* off = dir? off_from : off_to;
  int* end = dir? end_from : end_to;
  int* lrank = dir? lrank_from : lrank_to;
  __shared__ int sh[256];
  __shared__ int hist[64];
  int t = threadIdx.x;
  sh[t] = (t < NBLK)? bsum[dir*NBLK + t] : 0;
  if(t < 64) hist[t] = 0;
  __syncthreads();
  for(int d=1; d<256; d<<=1){
    int v = (t>=d)? sh[t-d] : 0;
    __syncthreads(); sh[t] += v; __syncthreads();
  }
  int bpre = (bb==0)? 0 : sh[bb-1];
  __syncthreads();
  int idx = bb*256 + t;
  int vals[NCH];
  int c = 0;
  if(idx < NNODES){
    int p = idx/PASSN, ln = idx - p*PASSN;
    const int* src = bhist2 + (size_t)(dir*NPASS*NCH + p*NCH)*PASSN + ln;
    #pragma unroll
    for(int ch=0;ch<NCH;ch++){ vals[ch] = src[ch*PASSN]; c += vals[ch]; }
  }
  sh[t] = c; __syncthreads();
  for(int d=1; d<256; d<<=1){
    int v = (t>=d)? sh[t-d] : 0;
    __syncthreads(); sh[t] += v; __syncthreads();
  }
  if(idx < NNODES){
    int o = bpre + ((t==0)? 0 : sh[t-1]);
    off[idx] = o;
    end[idx] = o + c;
    int run = o;
    #pragma unroll
    for(int ch=0;ch<NCH;ch++){
      cbase[(size_t)(dir*NCH + ch)*NNODES + idx] = run;
      run += vals[ch];
    }
    lrank[idx] = atomicAdd(&hist[min(c,63)], 1);
  }
  __syncthreads();
  if(t < 64) bhist[dir*64*NBLK + t*NBLK + bb] = hist[t];
}

__global__ __launch_bounds__(256) void k_bscan(const int* __restrict__ bhist, int* __restrict__ boff){
  const int N = 64*NBLK;
  const int CH = (N+255)/256;
  int dir = blockIdx.x;
  __shared__ int part[256];
  int t = threadIdx.x;
  int base = t*CH;
  int s = 0;
  for(int i=0;i<CH;i++){ int id=base+i; if(id<N) s += bhist[dir*N+id]; }
  part[t] = s; __syncthreads();
  for(int d=1; d<256; d<<=1){
    int v = (t>=d)? part[t-d] : 0;
    __syncthreads(); part[t] += v; __syncthreads();
  }
  int run = (t==0)? 0 : part[t-1];
  for(int i=0;i<CH;i++){
    int id = base+i;
    if(id<N){ boff[dir*N+id] = run; run += bhist[dir*N+id]; }
  }
}

__global__ void k_dplace(const int* __restrict__ off_to, const int* __restrict__ end_to,
                         const int* __restrict__ off_from, const int* __restrict__ end_from,
                         const int* __restrict__ boff,
                         const int* __restrict__ lrank_to, const int* __restrict__ lrank_from,
                         int* __restrict__ perm_to, int* __restrict__ perm_from){
  int idx = blockIdx.x*256 + threadIdx.x;
  if(idx >= NNODES) return;
  int blk = idx >> 8;
  int d1 = end_to[idx]-off_to[idx];
  perm_to[ boff[min(d1,63)*NBLK + blk] + lrank_to[idx] ] = idx;
  int d2 = end_from[idx]-off_from[idx];
  perm_from[ boff[64*NBLK + min(d2,63)*NBLK + blk] + lrank_from[idx] ] = idx;
}

__global__ void k_place(const int* __restrict__ i_link, const int* __restrict__ i_from,
                        const int* __restrict__ i_to,
                        const int* __restrict__ cbase,
                        const int* __restrict__ elrank_to, const int* __restrict__ elrank_from,
                        int* __restrict__ pay_to, int* __restrict__ pay_from){
  int e = blockIdx.x*256 + threadIdx.x;
  if(e >= NEDGES) return;
  int il = i_link[e], f = i_from[e], tt = i_to[e];
  int ch = e / ECHUNK;
  pay_to  [ cbase[(size_t)ch*NNODES + tt]            + elrank_to[e] ]   = f  | (il<<16);
  pay_from[ cbase[(size_t)(NCH+ch)*NNODES + f]       + elrank_from[e] ] = tt | (il<<16);
}

// ---------------- gathers (exp-domain fp16: tanh-sum via rcp only) ----------------
// lp/npart hold E = fp16(exp2(TANH_C*arg)); tanh = 1 - 2*rcp(E_lp*E_np + 1)
__global__ __launch_bounds__(256) void k_gather_x(
      const int* __restrict__ off_to, const int* __restrict__ end_to, const int* __restrict__ pay_to,
      const int* __restrict__ off_from, const int* __restrict__ end_from, const int* __restrict__ pay_from,
      const int* __restrict__ perm_to, const int* __restrict__ perm_from,
      const unsigned short* __restrict__ lp, const unsigned short* __restrict__ npart,
      unsigned short* __restrict__ xin, unsigned short* __restrict__ xout){
  int isOut = (blockIdx.x >= GN);
  int bb = isOut? blockIdx.x-GN : blockIdx.x;
  int slot = bb*16 + (threadIdx.x>>4);
  int n = isOut? perm_from[slot] : perm_to[slot];
  int c = (threadIdx.x & 15)*8;
  const int* off = isOut? off_from : off_to;
  const int* end = isOut? end_from : end_to;
  const int* pay = isOut? pay_from : pay_to;
  unsigned short* out = isOut? xout : xin;
  float acc[8];
  #pragma unroll
  for(int q=0;q<8;q++) acc[q]=0.f;
  int s = off[n], e = end[n];
  if(isOut){
    u16x8 bb8 = *(const u16x8*)(npart + (size_t)n*128 + c);
    float ef[8];
    #pragma unroll
    for(int q=0;q<8;q++) ef[q]=h2f(bb8[q]);
    int j = s;
    for(; j+1<e; j+=2){
      int p0 = pay[j], p1 = pay[j+1];
      u16x8 a0 = *(const u16x8*)(lp + (p0>>16)*128 + c);
      u16x8 a1 = *(const u16x8*)(lp + (p1>>16)*128 + c);
      #pragma unroll
      for(int q=0;q<8;q++){
        float v0 = h2f(a0[q])*ef[q];
        float v1 = h2f(a1[q])*ef[q];
        acc[q] += __builtin_amdgcn_rcpf(v0+1.0f) + __builtin_amdgcn_rcpf(v1+1.0f);
      }
    }
    if(j<e){
      int p0 = pay[j];
      u16x8 a0 = *(const u16x8*)(lp + (p0>>16)*128 + c);
      #pragma unroll
      for(int q=0;q<8;q++){
        float v0 = h2f(a0[q])*ef[q];
        acc[q] += __builtin_amdgcn_rcpf(v0+1.0f);
      }
    }
  } else {
    int j = s;
    for(; j+1<e; j+=2){
      int p0 = pay[j], p1 = pay[j+1];
      u16x8 a0 = *(const u16x8*)(lp + (p0>>16)*128 + c);
      u16x8 b0 = *(const u16x8*)(npart + (size_t)(p0&0xFFFF)*128 + c);
      u16x8 a1 = *(const u16x8*)(lp + (p1>>16)*128 + c);
      u16x8 b1 = *(const u16x8*)(npart + (size_t)(p1&0xFFFF)*128 + c);
      #pragma unroll
      for(int q=0;q<8;q++){
        float v0 = h2f(a0[q])*h2f(b0[q]);
        float v1 = h2f(a1[q])*h2f(b1[q]);
        acc[q] += __builtin_amdgcn_rcpf(v0+1.0f) + __builtin_amdgcn_rcpf(v1+1.0f);
      }
    }
    if(j<e){
      int p0 = pay[j];
      u16x8 a0 = *(const u16x8*)(lp + (p0>>16)*128 + c);
      u16x8 b0 = *(const u16x8*)(npart + (size_t)(p0&0xFFFF)*128 + c);
      #pragma unroll
      for(int q=0;q<8;q++){
        float v0 = h2f(a0[q])*h2f(b0[q]);
        acc[q] += __builtin_amdgcn_rcpf(v0+1.0f);
      }
    }
  }
  float deg = (float)(e - s);
  u16x8 o;
  #pragma unroll
  for(int q=0;q<8;q++) o[q]=f2b(deg - 2.0f*acc[q]);
  *(u16x8*)(out + (size_t)n*128 + c) = o;
}

__global__ __launch_bounds__(256) void k_gather_h(
      const int* __restrict__ off_to, const int* __restrict__ end_to, const int* __restrict__ pay_to,
      const int* __restrict__ off_from, const int* __restrict__ end_from, const int* __restrict__ pay_from,
      const int* __restrict__ perm_to, const int* __restrict__ perm_from,
      const unsigned short* __restrict__ src, unsigned short* __restrict__ hin,
      unsigned short* __restrict__ hout){
  int isOut = (blockIdx.x >= GN);
  int bb = isOut? blockIdx.x-GN : blockIdx.x;
  int slot = bb*16 + (threadIdx.x>>4);
  int n = isOut? perm_from[slot] : perm_to[slot];
  int c = (threadIdx.x & 15)*8;
  const int* off = isOut? off_from : off_to;
  const int* end = isOut? end_from : end_to;
  const int* pay = isOut? pay_from : pay_to;
  unsigned short* out = isOut? hout : hin;
  float acc[8];
  #pragma unroll
  for(int q=0;q<8;q++) acc[q]=0.f;
  int s = off[n], e = end[n];
  int j = s;
  for(; j+1<e; j+=2){
    int v0 = pay[j] & 0xFFFF, v1 = pay[j+1] & 0xFFFF;
    u16x8 a0 = *(const u16x8*)(src + (size_t)v0*128 + c);
    u16x8 a1 = *(const u16x8*)(src + (size_t)v1*128 + c);
    #pragma unroll
    for(int q=0;q<8;q++) acc[q] += b2f(a0[q]) + b2f(a1[q]);
  }
  if(j<e){
    int v0 = pay[j] & 0xFFFF;
    u16x8 a0 = *(const u16x8*)(src + (size_t)v0*128 + c);
    #pragma unroll
    for(int q=0;q<8;q++) acc[q] += b2f(a0[q]);
  }
  u16x8 o;
  #pragma unroll
  for(int q=0;q<8;q++) o[q]=f2b(acc[q]);
  *(u16x8*)(out + (size_t)n*128 + c) = o;
}

// ---------------- fused MFMA gate GEMM + LSTM cell (8 waves x 512 thr) ----------------
template<int P>
__device__ __forceinline__ const unsigned short* pick(
    const unsigned short* x0, const unsigned short* x1,
    const unsigned short* x2, const unsigned short* x3, int ks){
  if(P==2) return (ks<4)? x0 : x1;
  return (ks<4)? x0 : (ks<8)? x1 : (ks<12)? x2 : x3;
}

template<int P>
__global__ __launch_bounds__(512,2) void k_gates(
    const unsigned short* __restrict__ x0, const unsigned short* __restrict__ x1,
    const unsigned short* __restrict__ x2, const unsigned short* __restrict__ x3,
    const unsigned short* __restrict__ Wfrag,
    const float* __restrict__ bi, const float* __restrict__ bo,
    const float* __restrict__ bfg, const float* __restrict__ bu,
    unsigned short* __restrict__ c1b, unsigned short* __restrict__ h1,
    float* __restrict__ hout)
{
  __shared__ unsigned short As[2][64*36];
  int t = threadIdx.x;
  int m0 = blockIdx.x*64;
  int q = t>>6;              // wave id = output col-tile
  int l = t&63;
  int lm = l&15, kb = l>>4;
  f32x4 acc[4][4];           // [gate][rowtile]
  #pragma unroll
  for(int g=0;g<4;g++)
    #pragma unroll
    for(int r=0;r<4;r++) acc[g][r]=(f32x4){0.f,0.f,0.f,0.f};
  int sr = t>>3, sp = t&7;
  int sm = m0 + sr; if(sm >= NNODES) sm = NNODES-1;
  size_t soff = (size_t)sm*128 + sp*4;
  const int KSTEPS = P*4;
  u16x4 v0 = *(const u16x4*)(pick<P>(x0,x1,x2,x3,0) + soff + 0);
  *(u16x4*)(As[0] + sr*36 + sp*4) = v0;
  u16x4 vn = *(const u16x4*)(pick<P>(x0,x1,x2,x3,1) + soff + 32);
  __syncthreads();
  #pragma unroll
  for(int ks=0; ks<KSTEPS; ks++){
    int cur = ks&1;
    if(ks+1 < KSTEPS) *(u16x4*)(As[cur^1] + sr*36 + sp*4) = vn;
    if(ks+2 < KSTEPS)
      vn = *(const u16x4*)(pick<P>(x0,x1,x2,x3,ks+2) + soff + ((ks+2)&3)*32);
    s16x8 af[4];
    #pragma unroll
    for(int rt=0; rt<4; rt++)
      af[rt] = *(const s16x8*)(As[cur] + (16*rt+lm)*36 + kb*8);
    #pragma unroll
    for(int g=0;g<4;g++){
      if(P==2 && g==2) continue;     // layer 1: f-gate unused (c_prev = 0)
      int nt = 8*g + q;
      s16x8 bfr = *(const s16x8*)(Wfrag + (size_t)((ks*32 + nt)*64 + l)*8);
      #pragma unroll
      for(int rt=0; rt<4; rt++)
        acc[g][rt] = __builtin_amdgcn_mfma_f32_16x16x32_bf16(af[rt], bfr, acc[g][rt], 0,0,0);
    }
    __syncthreads();
  }
  int d = 16*q + lm;
  float vbi = bi[d], vbo = bo[d], vbu = bu[d];
  float vbf = (P==4)? bfg[d] : 0.f;
  #pragma unroll
  for(int rt=0; rt<4; rt++){
    #pragma unroll
    for(int reg=0; reg<4; reg++){
      int m = m0 + 16*rt + kb*4 + reg;
      if(m < NNODES){
        size_t o = (size_t)m*128 + d;
        float pi = acc[0][rt][reg] + vbi;
        float po = acc[1][rt][reg] + vbo;
        float pu = acc[3][rt][reg] + vbu;
        if(P==2){
          float c1v = sig_fast(pi)*tanh_fast(pu);
          float hv  = sig_fast(po)*tanh_fast(c1v);
          c1b[o] = f2b(c1v);
          h1[o] = f2b(hv);
        } else {
          float pf = acc[2][rt][reg] + vbf;
          float c2 = sig_fast(pf)*b2f(c1b[o]) + sig_fast(pi)*tanh_fast(pu);
          hout[o] = sig_fast(po)*tanh_fast(c2);
        }
      }
    }
  }
}

extern "C" void kernel_launch(void* const* d_in, const int* in_sizes, int n_in,
                              void* d_out, int out_size, void* d_ws, size_t ws_size,
                              hipStream_t stream){
  const int*   i_token  = (const int*)d_in[0];
  const int*   i_link   = (const int*)d_in[1];
  const int*   i_from   = (const int*)d_in[2];
  const int*   i_to     = (const int*)d_in[3];
  const float* emb_token= (const float*)d_in[4];
  const float* emb_link = (const float*)d_in[5];
  const float* Wc = (const float*)d_in[6];  const float* bc = (const float*)d_in[7];
  const float* Wl = (const float*)d_in[8];  const float* bl = (const float*)d_in[9];
  const float* Wi = (const float*)d_in[10]; const float* bi = (const float*)d_in[11];
  const float* Wo = (const float*)d_in[12]; const float* bo = (const float*)d_in[13];
  const float* Wf = (const float*)d_in[14]; const float* bf_ = (const float*)d_in[15];
  const float* Wu = (const float*)d_in[16]; const float* bu = (const float*)d_in[17];
  float* out = (float*)d_out;

  const size_t NB = (size_t)NNODES*128;
  unsigned short* c1b   = (unsigned short*)d_ws;
  unsigned short* npart = c1b + NB;
  unsigned short* xin   = npart + NB;
  unsigned short* xout  = xin + NB;
  unsigned short* hin   = xout + NB;
  unsigned short* houtb = hin + NB;
  unsigned short* h1    = houtb + NB;
  unsigned short* WgT   = h1 + NB;
  unsigned short* Wcfrag = WgT + 512*512;
  unsigned short* Wlfrag = Wcfrag + 320*128;
  unsigned short* linkpart = Wlfrag + 128*128;
  int* ia = (int*)(linkpart + 50*128);
  int* bhist2   = ia;                             // 2*NPASS*NCH*PASSN
  int* cbase    = bhist2 + 2*NPASS*NCH*PASSN;     // 2*NCH*NNODES
  int* off_to   = cbase + 2*NCH*NNODES;
  int* end_to   = off_to + NNODES;
  int* off_from = end_to + NNODES;
  int* end_from = off_from + NNODES;
  int* lrank_to = end_from + NNODES;
  int* lrank_from = lrank_to + NNODES;
  int* perm_to  = lrank_from + NNODES;
  int* perm_from= perm_to + NNODES;
  int* bsum     = perm_from + NNODES;             // 2*NBLK
  int* bhist    = bsum + 2*NBLK;                  // 2*64*NBLK
  int* boff     = bhist + 2*64*NBLK;              // 2*64*NBLK
  int* pay_to   = boff + 2*64*NBLK;
  int* pay_from = pay_to + NEDGES;
  int* elrank_to  = pay_from + NEDGES;
  int* elrank_from= elrank_to + NEDGES;

  const int GB = (NNODES + 63)/64;    // 782
  const int GE = (NEDGES + 255)/256;  // 3125

  // CSR build: LDS-privatized count (no global atomics) + scans + non-atomic place
  k_count<<<2*NPASS*NCH,1024,0,stream>>>(i_to, i_from, bhist2, elrank_to, elrank_from);
  k_scanA<<<2*NBLK,256,0,stream>>>(bhist2, bsum);
  k_scanBC<<<2*NBLK,256,0,stream>>>(bsum, bhist2, off_to, end_to, off_from, end_from,
                                    cbase, bhist, lrank_to, lrank_from);
  k_bscan<<<2,256,0,stream>>>(bhist, boff);
  k_dplace<<<NBLK,256,0,stream>>>(off_to, end_to, off_from, end_from, boff,
                                  lrank_to, lrank_from, perm_to, perm_from);
  k_place<<<GE,256,0,stream>>>(i_link, i_from, i_to, cbase, elrank_to, elrank_from,
                               pay_to, pay_from);

  // weight prepacks + node features (exp-domain fp16 lp/npart)
  k_prep_all<<<818,512,0,stream>>>(Wi, Wo, Wf, Wu, Wc, Wl, emb_link, bl,
                                   WgT, Wcfrag, Wlfrag, linkpart);
  k_ne<<<GB,256,0,stream>>>(i_token, emb_token, Wcfrag, bc, Wlfrag, npart);

  // x gathers (degree-sorted, exp-domain fp16)
  k_gather_x<<<2*GN,256,0,stream>>>(off_to, end_to, pay_to, off_from, end_from, pay_from,
                                    perm_to, perm_from, linkpart, npart, xin, xout);

  // layer 1 fused (K=256 over x; f-gate skipped)
  k_gates<2><<<GB,512,0,stream>>>(xin, xout, nullptr, nullptr, WgT,
                                  bi, bo, bf_, bu, c1b, h1, nullptr);

  // h gathers (degree-sorted)
  k_gather_h<<<2*GN,256,0,stream>>>(off_to, end_to, pay_to, off_from, end_from, pay_from,
                                    perm_to, perm_from, h1, hin, houtb);

  // layer 2 fused (K=512)
  k_gates<4><<<GB,512,0,stream>>>(xin, xout, hin, houtb, WgT,
                                  bi, bo, bf_, bu, c1b, nullptr, out);
}

// Round 21
// 276.188 us; speedup vs baseline: 1.9379x; 1.0039x over previous
//
#include <hip/hip_runtime.h>
#include <math.h>

#define NNODES 50000
#define NEDGES 800000
#define NBLK 196    // ceil(50000/256)
#define GN 3125     // ceil(50000/16)
#define NPASS 4     // node-range passes (12500 nodes -> 50KB LDS hist)
#define PASSN 12500
#define NCH 16      // edge chunks
#define ECHUNK (NEDGES/NCH)   // 50000

typedef __attribute__((ext_vector_type(8))) short s16x8;
typedef __attribute__((ext_vector_type(8))) unsigned short u16x8;
typedef __attribute__((ext_vector_type(4))) unsigned short u16x4;
typedef __attribute__((ext_vector_type(4))) float f32x4;

#define TANH_C 2.885390081777927f   // 2*log2(e)

__device__ __forceinline__ float tanh_fast(float x){
  float e = __builtin_amdgcn_exp2f(x*TANH_C);
  return 1.0f - 2.0f*__builtin_amdgcn_rcpf(e+1.0f);
}
__device__ __forceinline__ float sig_fast(float x){
  float e = __builtin_amdgcn_exp2f(-1.4426950408889634f*x);
  return __builtin_amdgcn_rcpf(1.0f+e);
}
__device__ __forceinline__ unsigned short f2b(float f){
  union{float f; unsigned u;} v; v.f = f;
  unsigned r = (v.u + 0x7FFFu + ((v.u>>16)&1u)) >> 16;
  return (unsigned short)r;
}
__device__ __forceinline__ float b2f(unsigned short b){
  union{unsigned u; float f;} v; v.u = ((unsigned)b)<<16; return v.f;
}
// fp16 encode/decode (exp-domain tables; inf/0 saturate correctly)
__device__ __forceinline__ unsigned short f2h(float f){
  _Float16 h = (_Float16)f;
  return __builtin_bit_cast(unsigned short, h);
}
__device__ __forceinline__ float h2f(unsigned short b){
  return (float)__builtin_bit_cast(_Float16, b);
}

// ---------- fused weight prep ----------
__global__ __launch_bounds__(512) void k_prep_all(
    const float* __restrict__ Wi, const float* __restrict__ Wo,
    const float* __restrict__ Wf, const float* __restrict__ Wu,
    const float* __restrict__ Wc, const float* __restrict__ Wl,
    const float* __restrict__ emb_link, const float* __restrict__ bl,
    unsigned short* __restrict__ Wfrag, unsigned short* __restrict__ Wcfrag,
    unsigned short* __restrict__ Wlfrag, unsigned short* __restrict__ lp){
  int b = blockIdx.x, t = threadIdx.x;
  if(b < 512){
    int n = b, k = t;
    const float* W = (n<128)? Wi : (n<256)? Wo : (n<384)? Wf : Wu;
    float v = W[(size_t)k*128 + (n&127)];
    int ks = k>>5, kb = (k>>3)&3, j = k&7;
    int nt = n>>4, lm = n&15;
    int l = lm + 16*kb;
    Wfrag[(size_t)(((ks*32 + nt)*64) + l)*8 + j] = f2b(v);
  } else if(b < 640){
    if(t < 320){
      int n = b-512, k = t;
      float v = (k < 300)? Wc[(size_t)k*128 + n] : 0.f;
      int ks = k>>5, kb = (k>>3)&3, j = k&7;
      int nt = n>>4, lm = n&15;
      int l = lm + 16*kb;
      Wcfrag[(size_t)(((ks*8 + nt)*64) + l)*8 + j] = f2b(v);
    }
  } else if(b < 768){
    if(t < 128){
      int n = b-640, k = t;
      float v = Wl[(size_t)(64+k)*128 + n];
      int ks = k>>5, kb = (k>>3)&3, j = k&7;
      int nt = n>>4, lm = n&15;
      int l = lm + 16*kb;
      Wlfrag[(size_t)(((ks*8 + nt)*64) + l)*8 + j] = f2b(v);
    }
  } else {
    if(t < 128){
      int l = b-768, d = t;
      float acc = bl[d];
      #pragma unroll 8
      for(int k=0;k<64;k++) acc += emb_link[l*64+k]*Wl[k*128+d];
      lp[l*128+d] = f2h(__builtin_amdgcn_exp2f(acc*TANH_C));   // E_lp (fp16)
    }
  }
}

// Fused: E1 = tanh(gather(emb_token)@Wc + bc); E_np = fp16(exp2(TANH_C*(E1@Wl[64:192])))
__global__ __launch_bounds__(256,2) void k_ne(const int* __restrict__ i_token,
      const float* __restrict__ emb_token, const unsigned short* __restrict__ Wcfrag,
      const float* __restrict__ bc, const unsigned short* __restrict__ Wlfrag,
      unsigned short* __restrict__ npart){
  __shared__ unsigned short As[64*36];
  __shared__ unsigned short E1[64*132];
  __shared__ int rowidx[64];
  int t = threadIdx.x;
  int m0 = blockIdx.x*64;
  if(t<64){ int m=m0+t; rowidx[t]=(m<NNODES)? i_token[m]:0; }
  int w=t>>6, l=t&63, lm=l&15, kb=l>>4;
  f32x4 acc[2][4];
  #pragma unroll
  for(int c=0;c<2;c++)
    #pragma unroll
    for(int r=0;r<4;r++) acc[c][r]=(f32x4){0.f,0.f,0.f,0.f};
  int sr=t>>2, sp=t&3;
  __syncthreads();
  const float* srcrow = emb_token + (size_t)rowidx[sr]*300;
  for(int ks=0; ks<10; ks++){
    int k0 = ks*32 + sp*8;
    u16x8 v;
    #pragma unroll
    for(int j=0;j<8;j++){ int k=k0+j; v[j] = (k<300)? f2b(srcrow[k]) : (unsigned short)0; }
    if(ks) __syncthreads();
    *(u16x8*)(As + sr*36 + sp*8) = v;
    __syncthreads();
    s16x8 af[4];
    #pragma unroll
    for(int rt=0;rt<4;rt++) af[rt] = *(const s16x8*)(As + (16*rt+lm)*36 + kb*8);
    #pragma unroll
    for(int c=0;c<2;c++){
      int nt = 2*w + c;
      s16x8 bfr = *(const s16x8*)(Wcfrag + (size_t)((ks*8+nt)*64 + l)*8);
      #pragma unroll
      for(int rt=0;rt<4;rt++)
        acc[c][rt] = __builtin_amdgcn_mfma_f32_16x16x32_bf16(af[rt], bfr, acc[c][rt],0,0,0);
    }
  }
  __syncthreads();
  #pragma unroll
  for(int c=0;c<2;c++){
    int d = 16*(2*w+c) + lm;
    float vb = bc[d];
    #pragma unroll
    for(int rt=0;rt<4;rt++)
      #pragma unroll
      for(int reg=0;reg<4;reg++){
        int r = 16*rt + kb*4 + reg;
        E1[r*132 + d] = f2b(tanh_fast(acc[c][rt][reg]+vb));
      }
  }
  __syncthreads();
  f32x4 acc2[2][4];
  #pragma unroll
  for(int c=0;c<2;c++)
    #pragma unroll
    for(int r=0;r<4;r++) acc2[c][r]=(f32x4){0.f,0.f,0.f,0.f};
  #pragma unroll
  for(int ks=0; ks<4; ks++){
    s16x8 af[4];
    #pragma unroll
    for(int rt=0;rt<4;rt++) af[rt] = *(const s16x8*)(E1 + (16*rt+lm)*132 + ks*32 + kb*8);
    #pragma unroll
    for(int c=0;c<2;c++){
      int nt = 2*w + c;
      s16x8 bfr = *(const s16x8*)(Wlfrag + (size_t)((ks*8+nt)*64 + l)*8);
      #pragma unroll
      for(int rt=0;rt<4;rt++)
        acc2[c][rt] = __builtin_amdgcn_mfma_f32_16x16x32_bf16(af[rt], bfr, acc2[c][rt],0,0,0);
    }
  }
  #pragma unroll
  for(int c=0;c<2;c++){
    int d = 16*(2*w+c) + lm;
    #pragma unroll
    for(int rt=0;rt<4;rt++)
      #pragma unroll
      for(int reg=0;reg<4;reg++){
        int m = m0 + 16*rt + kb*4 + reg;
        if(m < NNODES)
          npart[(size_t)m*128 + d] = f2h(__builtin_amdgcn_exp2f(acc2[c][rt][reg]*TANH_C)); // E_np (fp16)
      }
  }
}

// ---------------- CSR build: LDS-privatized chunked counting sort ----------------
__global__ __launch_bounds__(1024) void k_count(const int* __restrict__ i_to,
      const int* __restrict__ i_from, int* __restrict__ bhist2,
      int* __restrict__ elrank_to, int* __restrict__ elrank_from){
  __shared__ int hist[PASSN];
  int b = blockIdx.x;
  int dir = b / (NPASS*NCH);
  int rem = b - dir*(NPASS*NCH);
  int p = rem / NCH, ch = rem - p*NCH;
  const int* ids = dir ? i_from : i_to;
  int* elrank = dir ? elrank_from : elrank_to;
  int t = threadIdx.x;
  for(int i=t;i<PASSN;i+=1024) hist[i]=0;
  __syncthreads();
  int base = ch*ECHUNK;
  for(int e=base+t; e<base+ECHUNK; e+=1024){
    int r = ids[e] - p*PASSN;
    if((unsigned)r < PASSN) elrank[e] = atomicAdd(&hist[r],1);
  }
  __syncthreads();
  int* dst = bhist2 + (size_t)b*PASSN;
  for(int i=t;i<PASSN;i+=1024) dst[i]=hist[i];
}

__global__ __launch_bounds__(256) void k_scanA(const int* __restrict__ bhist2,
      int* __restrict__ bsum){
  int b = blockIdx.x; int dir = (b >= NBLK); int bb = dir? b-NBLK : b;
  int t = threadIdx.x;
  int idx = bb*256 + t;
  int c = 0;
  if(idx < NNODES){
    int p = idx/PASSN, ln = idx - p*PASSN;
    const int* src = bhist2 + (size_t)(dir*NPASS*NCH + p*NCH)*PASSN + ln;
    #pragma unroll
    for(int ch=0;ch<NCH;ch++) c += src[ch*PASSN];
  }
  __shared__ int red[256];
  red[t] = c; __syncthreads();
  for(int s=128;s>0;s>>=1){ if(t<s) red[t]+=red[t+s]; __syncthreads(); }
  if(t==0) bsum[b] = red[0];
}

__global__ __launch_bounds__(256) void k_scanBC(const int* __restrict__ bsum,
      const int* __restrict__ bhist2,
      int* __restrict__ off_to, int* __restrict__ end_to,
      int* __restrict__ off_from, int* __restrict__ end_from,
      int* __restrict__ cbase,
      int* __restrict__ bhist, int* __restrict__ lrank_to, int* __restrict__ lrank_from){
  int b = blockIdx.x; int dir = (b >= NBLK); int bb = dir? b-NBLK : b;
  int* off = dir? off_from : off_to;
  int* end = dir? end_from : end_to;
  int* lrank = dir? lrank_from : lrank_to;
  __shared__ int sh[256];
  __shared__ int hist[64];
  int t = threadIdx.x;
  sh[t] = (t < NBLK)? bsum[dir*NBLK + t] : 0;
  if(t < 64) hist[t] = 0;
  __syncthreads();
  for(int d=1; d<256; d<<=1){
    int v = (t>=d)? sh[t-d] : 0;
    __syncthreads(); sh[t] += v; __syncthreads();
  }
  int bpre = (bb==0)? 0 : sh[bb-1];
  __syncthreads();
  int idx = bb*256 + t;
  int vals[NCH];
  int c = 0;
  if(idx < NNODES){
    int p = idx/PASSN, ln = idx - p*PASSN;
    const int* src = bhist2 + (size_t)(dir*NPASS*NCH + p*NCH)*PASSN + ln;
    #pragma unroll
    for(int ch=0;ch<NCH;ch++){ vals[ch] = src[ch*PASSN]; c += vals[ch]; }
  }
  sh[t] = c; __syncthreads();
  for(int d=1; d<256; d<<=1){
    int v = (t>=d)? sh[t-d] : 0;
    __syncthreads(); sh[t] += v; __syncthreads();
  }
  if(idx < NNODES){
    int o = bpre + ((t==0)? 0 : sh[t-1]);
    off[idx] = o;
    end[idx] = o + c;
    int run = o;
    #pragma unroll
    for(int ch=0;ch<NCH;ch++){
      cbase[(size_t)(dir*NCH + ch)*NNODES + idx] = run;
      run += vals[ch];
    }
    lrank[idx] = atomicAdd(&hist[min(c,63)], 1);
  }
  __syncthreads();
  if(t < 64) bhist[dir*64*NBLK + t*NBLK + bb] = hist[t];
}

__global__ __launch_bounds__(256) void k_bscan(const int* __restrict__ bhist, int* __restrict__ boff){
  const int N = 64*NBLK;
  const int CH = (N+255)/256;
  int dir = blockIdx.x;
  __shared__ int part[256];
  int t = threadIdx.x;
  int base = t*CH;
  int s = 0;
  for(int i=0;i<CH;i++){ int id=base+i; if(id<N) s += bhist[dir*N+id]; }
  part[t] = s; __syncthreads();
  for(int d=1; d<256; d<<=1){
    int v = (t>=d)? part[t-d] : 0;
    __syncthreads(); part[t] += v; __syncthreads();
  }
  int run = (t==0)? 0 : part[t-1];
  for(int i=0;i<CH;i++){
    int id = base+i;
    if(id<N){ boff[dir*N+id] = run; run += bhist[dir*N+id]; }
  }
}

__global__ void k_dplace(const int* __restrict__ off_to, const int* __restrict__ end_to,
                         const int* __restrict__ off_from, const int* __restrict__ end_from,
                         const int* __restrict__ boff,
                         const int* __restrict__ lrank_to, const int* __restrict__ lrank_from,
                         int* __restrict__ perm_to, int* __restrict__ perm_from){
  int idx = blockIdx.x*256 + threadIdx.x;
  if(idx >= NNODES) return;
  int blk = idx >> 8;
  int d1 = end_to[idx]-off_to[idx];
  perm_to[ boff[min(d1,63)*NBLK + blk] + lrank_to[idx] ] = idx;
  int d2 = end_from[idx]-off_from[idx];
  perm_from[ boff[64*NBLK + min(d2,63)*NBLK + blk] + lrank_from[idx] ] = idx;
}

__global__ void k_place(const int* __restrict__ i_link, const int* __restrict__ i_from,
                        const int* __restrict__ i_to,
                        const int* __restrict__ cbase,
                        const int* __restrict__ elrank_to, const int* __restrict__ elrank_from,
                        int* __restrict__ pay_to, int* __restrict__ pay_from){
  int e = blockIdx.x*256 + threadIdx.x;
  if(e >= NEDGES) return;
  int il = i_link[e], f = i_from[e], tt = i_to[e];
  int ch = e / ECHUNK;
  pay_to  [ cbase[(size_t)ch*NNODES + tt]            + elrank_to[e] ]   = f  | (il<<16);
  pay_from[ cbase[(size_t)(NCH+ch)*NNODES + f]       + elrank_from[e] ] = tt | (il<<16);
}

// ---------------- gathers (exp-domain fp16, 4x unrolled for MLP) ----------------
__global__ __launch_bounds__(256) void k_gather_x(
      const int* __restrict__ off_to, const int* __restrict__ end_to, const int* __restrict__ pay_to,
      const int* __restrict__ off_from, const int* __restrict__ end_from, const int* __restrict__ pay_from,
      const int* __restrict__ perm_to, const int* __restrict__ perm_from,
      const unsigned short* __restrict__ lp, const unsigned short* __restrict__ npart,
      unsigned short* __restrict__ xin, unsigned short* __restrict__ xout){
  int isOut = (blockIdx.x >= GN);
  int bb = isOut? blockIdx.x-GN : blockIdx.x;
  int slot = bb*16 + (threadIdx.x>>4);
  int n = isOut? perm_from[slot] : perm_to[slot];
  int c = (threadIdx.x & 15)*8;
  const int* off = isOut? off_from : off_to;
  const int* end = isOut? end_from : end_to;
  const int* pay = isOut? pay_from : pay_to;
  unsigned short* out = isOut? xout : xin;
  float acc[8];
  #pragma unroll
  for(int q=0;q<8;q++) acc[q]=0.f;
  int s = off[n], e = end[n];
  if(isOut){
    u16x8 bb8 = *(const u16x8*)(npart + (size_t)n*128 + c);
    float ef[8];
    #pragma unroll
    for(int q=0;q<8;q++) ef[q]=h2f(bb8[q]);
    int j = s;
    for(; j+3<e; j+=4){
      u16x8 a0 = *(const u16x8*)(lp + (pay[j]>>16)*128 + c);
      u16x8 a1 = *(const u16x8*)(lp + (pay[j+1]>>16)*128 + c);
      u16x8 a2 = *(const u16x8*)(lp + (pay[j+2]>>16)*128 + c);
      u16x8 a3 = *(const u16x8*)(lp + (pay[j+3]>>16)*128 + c);
      #pragma unroll
      for(int q=0;q<8;q++){
        acc[q] += __builtin_amdgcn_rcpf(h2f(a0[q])*ef[q]+1.0f)
                + __builtin_amdgcn_rcpf(h2f(a1[q])*ef[q]+1.0f)
                + __builtin_amdgcn_rcpf(h2f(a2[q])*ef[q]+1.0f)
                + __builtin_amdgcn_rcpf(h2f(a3[q])*ef[q]+1.0f);
      }
    }
    for(; j<e; j++){
      u16x8 a0 = *(const u16x8*)(lp + (pay[j]>>16)*128 + c);
      #pragma unroll
      for(int q=0;q<8;q++)
        acc[q] += __builtin_amdgcn_rcpf(h2f(a0[q])*ef[q]+1.0f);
    }
  } else {
    int j = s;
    for(; j+3<e; j+=4){
      int p0 = pay[j], p1 = pay[j+1], p2 = pay[j+2], p3 = pay[j+3];
      u16x8 a0 = *(const u16x8*)(lp + (p0>>16)*128 + c);
      u16x8 b0 = *(const u16x8*)(npart + (size_t)(p0&0xFFFF)*128 + c);
      u16x8 a1 = *(const u16x8*)(lp + (p1>>16)*128 + c);
      u16x8 b1 = *(const u16x8*)(npart + (size_t)(p1&0xFFFF)*128 + c);
      u16x8 a2 = *(const u16x8*)(lp + (p2>>16)*128 + c);
      u16x8 b2 = *(const u16x8*)(npart + (size_t)(p2&0xFFFF)*128 + c);
      u16x8 a3 = *(const u16x8*)(lp + (p3>>16)*128 + c);
      u16x8 b3 = *(const u16x8*)(npart + (size_t)(p3&0xFFFF)*128 + c);
      #pragma unroll
      for(int q=0;q<8;q++){
        acc[q] += __builtin_amdgcn_rcpf(h2f(a0[q])*h2f(b0[q])+1.0f)
                + __builtin_amdgcn_rcpf(h2f(a1[q])*h2f(b1[q])+1.0f)
                + __builtin_amdgcn_rcpf(h2f(a2[q])*h2f(b2[q])+1.0f)
                + __builtin_amdgcn_rcpf(h2f(a3[q])*h2f(b3[q])+1.0f);
      }
    }
    for(; j<e; j++){
      int p0 = pay[j];
      u16x8 a0 = *(const u16x8*)(lp + (p0>>16)*128 + c);
      u16x8 b0 = *(const u16x8*)(npart + (size_t)(p0&0xFFFF)*128 + c);
      #pragma unroll
      for(int q=0;q<8;q++)
        acc[q] += __builtin_amdgcn_rcpf(h2f(a0[q])*h2f(b0[q])+1.0f);
    }
  }
  float deg = (float)(e - s);
  u16x8 o;
  #pragma unroll
  for(int q=0;q<8;q++) o[q]=f2b(deg - 2.0f*acc[q]);
  *(u16x8*)(out + (size_t)n*128 + c) = o;
}

__global__ __launch_bounds__(256) void k_gather_h(
      const int* __restrict__ off_to, const int* __restrict__ end_to, const int* __restrict__ pay_to,
      const int* __restrict__ off_from, const int* __restrict__ end_from, const int* __restrict__ pay_from,
      const int* __restrict__ perm_to, const int* __restrict__ perm_from,
      const unsigned short* __restrict__ src, unsigned short* __restrict__ hin,
      unsigned short* __restrict__ hout){
  int isOut = (blockIdx.x >= GN);
  int bb = isOut? blockIdx.x-GN : blockIdx.x;
  int slot = bb*16 + (threadIdx.x>>4);
  int n = isOut? perm_from[slot] : perm_to[slot];
  int c = (threadIdx.x & 15)*8;
  const int* off = isOut? off_from : off_to;
  const int* end = isOut? end_from : end_to;
  const int* pay = isOut? pay_from : pay_to;
  unsigned short* out = isOut? hout : hin;
  float acc[8];
  #pragma unroll
  for(int q=0;q<8;q++) acc[q]=0.f;
  int s = off[n], e = end[n];
  int j = s;
  for(; j+3<e; j+=4){
    u16x8 a0 = *(const u16x8*)(src + (size_t)(pay[j]&0xFFFF)*128 + c);
    u16x8 a1 = *(const u16x8*)(src + (size_t)(pay[j+1]&0xFFFF)*128 + c);
    u16x8 a2 = *(const u16x8*)(src + (size_t)(pay[j+2]&0xFFFF)*128 + c);
    u16x8 a3 = *(const u16x8*)(src + (size_t)(pay[j+3]&0xFFFF)*128 + c);
    #pragma unroll
    for(int q=0;q<8;q++)
      acc[q] += (b2f(a0[q]) + b2f(a1[q])) + (b2f(a2[q]) + b2f(a3[q]));
  }
  for(; j<e; j++){
    u16x8 a0 = *(const u16x8*)(src + (size_t)(pay[j]&0xFFFF)*128 + c);
    #pragma unroll
    for(int q=0;q<8;q++) acc[q] += b2f(a0[q]);
  }
  u16x8 o;
  #pragma unroll
  for(int q=0;q<8;q++) o[q]=f2b(acc[q]);
  *(u16x8*)(out + (size_t)n*128 + c) = o;
}

// ---------------- fused MFMA gate GEMM + LSTM cell (8 waves x 512 thr) ----------------
template<int P>
__device__ __forceinline__ const unsigned short* pick(
    const unsigned short* x0, const unsigned short* x1,
    const unsigned short* x2, const unsigned short* x3, int ks){
  if(P==2) return (ks<4)? x0 : x1;
  return (ks<4)? x0 : (ks<8)? x1 : (ks<12)? x2 : x3;
}

template<int P>
__global__ __launch_bounds__(512,2) void k_gates(
    const unsigned short* __restrict__ x0, const unsigned short* __restrict__ x1,
    const unsigned short* __restrict__ x2, const unsigned short* __restrict__ x3,
    const unsigned short* __restrict__ Wfrag,
    const float* __restrict__ bi, const float* __restrict__ bo,
    const float* __restrict__ bfg, const float* __restrict__ bu,
    unsigned short* __restrict__ c1b, unsigned short* __restrict__ h1,
    float* __restrict__ hout)
{
  __shared__ unsigned short As[2][64*36];
  int t = threadIdx.x;
  int m0 = blockIdx.x*64;
  int q = t>>6;              // wave id = output col-tile
  int l = t&63;
  int lm = l&15, kb = l>>4;
  f32x4 acc[4][4];           // [gate][rowtile]
  #pragma unroll
  for(int g=0;g<4;g++)
    #pragma unroll
    for(int r=0;r<4;r++) acc[g][r]=(f32x4){0.f,0.f,0.f,0.f};
  int sr = t>>3, sp = t&7;
  int sm = m0 + sr; if(sm >= NNODES) sm = NNODES-1;
  size_t soff = (size_t)sm*128 + sp*4;
  const int KSTEPS = P*4;
  u16x4 v0 = *(const u16x4*)(pick<P>(x0,x1,x2,x3,0) + soff + 0);
  *(u16x4*)(As[0] + sr*36 + sp*4) = v0;
  u16x4 vn = *(const u16x4*)(pick<P>(x0,x1,x2,x3,1) + soff + 32);
  __syncthreads();
  #pragma unroll
  for(int ks=0; ks<KSTEPS; ks++){
    int cur = ks&1;
    if(ks+1 < KSTEPS) *(u16x4*)(As[cur^1] + sr*36 + sp*4) = vn;
    if(ks+2 < KSTEPS)
      vn = *(const u16x4*)(pick<P>(x0,x1,x2,x3,ks+2) + soff + ((ks+2)&3)*32);
    s16x8 af[4];
    #pragma unroll
    for(int rt=0; rt<4; rt++)
      af[rt] = *(const s16x8*)(As[cur] + (16*rt+lm)*36 + kb*8);
    #pragma unroll
    for(int g=0;g<4;g++){
      if(P==2 && g==2) continue;     // layer 1: f-gate unused (c_prev = 0)
      int nt = 8*g + q;
      s16x8 bfr = *(const s16x8*)(Wfrag + (size_t)((ks*32 + nt)*64 + l)*8);
      #pragma unroll
      for(int rt=0; rt<4; rt++)
        acc[g][rt] = __builtin_amdgcn_mfma_f32_16x16x32_bf16(af[rt], bfr, acc[g][rt], 0,0,0);
    }
    __syncthreads();
  }
  int d = 16*q + lm;
  float vbi = bi[d], vbo = bo[d], vbu = bu[d];
  float vbf = (P==4)? bfg[d] : 0.f;
  #pragma unroll
  for(int rt=0; rt<4; rt++){
    #pragma unroll
    for(int reg=0; reg<4; reg++){
      int m = m0 + 16*rt + kb*4 + reg;
      if(m < NNODES){
        size_t o = (size_t)m*128 + d;
        float pi = acc[0][rt][reg] + vbi;
        float po = acc[1][rt][reg] + vbo;
        float pu = acc[3][rt][reg] + vbu;
        if(P==2){
          float c1v = sig_fast(pi)*tanh_fast(pu);
          float hv  = sig_fast(po)*tanh_fast(c1v);
          c1b[o] = f2b(c1v);
          h1[o] = f2b(hv);
        } else {
          float pf = acc[2][rt][reg] + vbf;
          float c2 = sig_fast(pf)*b2f(c1b[o]) + sig_fast(pi)*tanh_fast(pu);
          hout[o] = sig_fast(po)*tanh_fast(c2);
        }
      }
    }
  }
}

extern "C" void kernel_launch(void* const* d_in, const int* in_sizes, int n_in,
                              void* d_out, int out_size, void* d_ws, size_t ws_size,
                              hipStream_t stream){
  const int*   i_token  = (const int*)d_in[0];
  const int*   i_link   = (const int*)d_in[1];
  const int*   i_from   = (const int*)d_in[2];
  const int*   i_to     = (const int*)d_in[3];
  const float* emb_token= (const float*)d_in[4];
  const float* emb_link = (const float*)d_in[5];
  const float* Wc = (const float*)d_in[6];  const float* bc = (const float*)d_in[7];
  const float* Wl = (const float*)d_in[8];  const float* bl = (const float*)d_in[9];
  const float* Wi = (const float*)d_in[10]; const float* bi = (const float*)d_in[11];
  const float* Wo = (const float*)d_in[12]; const float* bo = (const float*)d_in[13];
  const float* Wf = (const float*)d_in[14]; const float* bf_ = (const float*)d_in[15];
  const float* Wu = (const float*)d_in[16]; const float* bu = (const float*)d_in[17];
  float* out = (float*)d_out;

  const size_t NB = (size_t)NNODES*128;
  unsigned short* c1b   = (unsigned short*)d_ws;
  unsigned short* npart = c1b + NB;
  unsigned short* xin   = npart + NB;
  unsigned short* xout  = xin + NB;
  unsigned short* hin   = xout + NB;
  unsigned short* houtb = hin + NB;
  unsigned short* h1    = houtb + NB;
  unsigned short* WgT   = h1 + NB;
  unsigned short* Wcfrag = WgT + 512*512;
  unsigned short* Wlfrag = Wcfrag + 320*128;
  unsigned short* linkpart = Wlfrag + 128*128;
  int* ia = (int*)(linkpart + 50*128);
  int* bhist2   = ia;                             // 2*NPASS*NCH*PASSN
  int* cbase    = bhist2 + 2*NPASS*NCH*PASSN;     // 2*NCH*NNODES
  int* off_to   = cbase + 2*NCH*NNODES;
  int* end_to   = off_to + NNODES;
  int* off_from = end_to + NNODES;
  int* end_from = off_from + NNODES;
  int* lrank_to = end_from + NNODES;
  int* lrank_from = lrank_to + NNODES;
  int* perm_to  = lrank_from + NNODES;
  int* perm_from= perm_to + NNODES;
  int* bsum     = perm_from + NNODES;             // 2*NBLK
  int* bhist    = bsum + 2*NBLK;                  // 2*64*NBLK
  int* boff     = bhist + 2*64*NBLK;              // 2*64*NBLK
  int* pay_to   = boff + 2*64*NBLK;
  int* pay_from = pay_to + NEDGES;
  int* elrank_to  = pay_from + NEDGES;
  int* elrank_from= elrank_to + NEDGES;

  const int GB = (NNODES + 63)/64;    // 782
  const int GE = (NEDGES + 255)/256;  // 3125

  // CSR build: LDS-privatized count (no global atomics) + scans + non-atomic place
  k_count<<<2*NPASS*NCH,1024,0,stream>>>(i_to, i_from, bhist2, elrank_to, elrank_from);
  k_scanA<<<2*NBLK,256,0,stream>>>(bhist2, bsum);
  k_scanBC<<<2*NBLK,256,0,stream>>>(bsum, bhist2, off_to, end_to, off_from, end_from,
                                    cbase, bhist, lrank_to, lrank_from);
  k_bscan<<<2,256,0,stream>>>(bhist, boff);
  k_dplace<<<NBLK,256,0,stream>>>(off_to, end_to, off_from, end_from, boff,
                                  lrank_to, lrank_from, perm_to, perm_from);
  k_place<<<GE,256,0,stream>>>(i_link, i_from, i_to, cbase, elrank_to, elrank_from,
                               pay_to, pay_from);

  // weight prepacks + node features (exp-domain fp16 lp/npart)
  k_prep_all<<<818,512,0,stream>>>(Wi, Wo, Wf, Wu, Wc, Wl, emb_link, bl,
                                   WgT, Wcfrag, Wlfrag, linkpart);
  k_ne<<<GB,256,0,stream>>>(i_token, emb_token, Wcfrag, bc, Wlfrag, npart);

  // x gathers (degree-sorted, exp-domain fp16, 4x unrolled)
  k_gather_x<<<2*GN,256,0,stream>>>(off_to, end_to, pay_to, off_from, end_from, pay_from,
                                    perm_to, perm_from, linkpart, npart, xin, xout);

  // layer 1 fused (K=256 over x; f-gate skipped)
  k_gates<2><<<GB,512,0,stream>>>(xin, xout, nullptr, nullptr, WgT,
                                  bi, bo, bf_, bu, c1b, h1, nullptr);

  // h gathers (degree-sorted, 4x unrolled)
  k_gather_h<<<2*GN,256,0,stream>>>(off_to, end_to, pay_to, off_from, end_from, pay_from,
                                    perm_to, perm_from, h1, hin, houtb);

  // layer 2 fused (K=512)
  k_gates<4><<<GB,512,0,stream>>>(xin, xout, hin, houtb, WgT,
                                  bi, bo, bf_, bu, c1b, nullptr, out);
}